// Round 8
// baseline (839.326 us; speedup 1.0000x reference)
//
#include <hip/hip_runtime.h>
#include <math.h>

// Problem constants
static constexpr int Bb = 128;    // batch
static constexpr int Tt = 64;     // seq len
static constexpr int Ee = 512;    // embed dim
static constexpr int Hh = 1024;   // hidden
static constexpr int Vv = 10000;  // vocab
static constexpr int G  = 4 * Hh; // 4096 gates
static constexpr int Vpad = 10240; // 40*256, zero-padded vocab rows (256-tiles)

typedef __attribute__((ext_vector_type(8))) short short8;
typedef __attribute__((ext_vector_type(4))) float floatx4;

__device__ __forceinline__ unsigned short f2bf(float f) {
    unsigned u = __float_as_uint(f);
    return (unsigned short)((u + 0x7fffu + ((u >> 16) & 1u)) >> 16);  // RNE
}

__device__ __forceinline__ void gload16(const void* g, void* l) {
    __builtin_amdgcn_global_load_lds(
        (const __attribute__((address_space(1))) void*)g,
        (__attribute__((address_space(3))) void*)l, 16, 0, 0);
}

// fast transcendentals (v_exp_f32 + v_rcp_f32; ~1e-6 rel err, far below bf16)
__device__ __forceinline__ float sigmoid_fast(float x) {
    return __builtin_amdgcn_rcpf(1.f + __expf(-x));
}
__device__ __forceinline__ float tanh_fast(float x) {
    float e = __expf(-2.f * fabsf(x));
    float t = (1.f - e) * __builtin_amdgcn_rcpf(1.f + e);
    return copysignf(t, x);
}

// ---------------------------------------------------------------------------
// f32 -> bf16 convert, with zero-padding up to npad elements
// ---------------------------------------------------------------------------
__global__ __launch_bounds__(256)
void cvt_bf16(const float* __restrict__ s, unsigned short* __restrict__ d,
              int n, int npad) {
    int i8 = (blockIdx.x * 256 + threadIdx.x) * 8;
    if (i8 >= npad) return;
    short8 v;
    #pragma unroll
    for (int j = 0; j < 8; ++j) {
        int e = i8 + j;
        float f = (e < n) ? s[e] : 0.f;
        v[j] = (short)f2bf(f);
    }
    *reinterpret_cast<short8*>(d + i8) = v;
}

// ---------------------------------------------------------------------------
// Gather xs[t*B+b, :] = bf16( t==0 ? features[b,:] : embed_W[captions[b,t],:] )
// ---------------------------------------------------------------------------
__global__ __launch_bounds__(256)
void gather_xs(const float* __restrict__ features,
               const int* __restrict__ captions,
               const float* __restrict__ embed_W,
               unsigned short* __restrict__ xs) {
    int idx = blockIdx.x * 256 + threadIdx.x;   // T*B*(E/8)
    int m  = idx >> 6;                          // row, E/8 = 64 chunks per row
    int c8 = (idx & 63) * 8;
    int t = m >> 7;                             // m / B
    int b = m & 127;                            // m % B
    const float* src;
    if (t == 0) {
        src = features + (size_t)b * Ee + c8;
    } else {
        int tok = captions[(size_t)b * Tt + t];
        src = embed_W + (size_t)tok * Ee + c8;
    }
    short8 v;
    #pragma unroll
    for (int j = 0; j < 8; ++j) v[j] = (short)f2bf(src[j]);
    *reinterpret_cast<short8*>(xs + (size_t)m * Ee + c8) = v;
}

// ---------------------------------------------------------------------------
// 256x256-tile bf16 MFMA GEMM, BK=32, 4-deep circular LDS pipeline.
//   (unchanged from v10 — proven passing)
// ---------------------------------------------------------------------------
__device__ __forceinline__ void stage_half(
    const unsigned short* __restrict__ Gsrc, int Kdim, int rowbase, int k0,
    unsigned short* ldsbase, int tid) {
    // one 16B load per thread covers the 8 KB half-tile (128 rows x 32 k)
    int e = tid * 16;                     // byte offset in half-tile
    int r = e >> 6;                       // row 0..127
    int c = e & 63;                       // byte in row (0/16/32/48)
    int c_log = c ^ ((r & 3) << 4);       // inverse-swizzled source column
    gload16(Gsrc + (size_t)(rowbase + r) * Kdim + k0 + (c_log >> 1),
            ldsbase + tid * 8);
}

template<int MODE>
__global__ __launch_bounds__(512, 2)
void gemm256(const unsigned short* __restrict__ A,
             const unsigned short* __restrict__ Bm,
             int M, int N, int K,
             const float* __restrict__ bias0, const float* __restrict__ bias1,
             float* __restrict__ C) {
    constexpr int BK = 32;
    __shared__ unsigned short lds[4 * 2 * 256 * BK];   // 128 KB

    const int nwg = gridDim.x * gridDim.y;
    const int flat = blockIdx.y * gridDim.x + blockIdx.x;
    const int tix = (flat & 7) * (nwg >> 3) + (flat >> 3);
    const int bx = tix % gridDim.x;
    const int by = tix / gridDim.x;

    const int tid  = threadIdx.x;
    const int wid  = tid >> 6;      // 0..7
    const int lane = tid & 63;
    const int wm = wid >> 2;        // 0..1  (M half)
    const int wn = wid & 3;         // 0..3  (N quarter)
    const int row0 = bx * 256;
    const int col0 = by * 256;
    const int l15 = lane & 15;
    const int kq  = lane >> 4;

    const int NT = K / BK;

    // per-thread ds_read bases (shorts); swizzled slot kq ^ (row&3), row&3==l15&3
    const int swz = (kq ^ (l15 & 3)) * 8;
    const int arow_s = wm * 4096 + l15 * 32 + swz;
    const int brow_s = 8192 + (wn >> 1) * 4096 + ((wn & 1) * 64 + l15) * 32 + swz;

    floatx4 acc[8][4];
    #pragma unroll
    for (int i = 0; i < 8; ++i)
        #pragma unroll
        for (int j = 0; j < 4; ++j) acc[i][j] = (floatx4)0.f;

    // prologue: stage tiles 0 and 1 (4 half-tiles each)
    stage_half(A,  K, row0,       0,  &lds[0],     tid);
    stage_half(A,  K, row0 + 128, 0,  &lds[4096],  tid);
    stage_half(Bm, K, col0,       0,  &lds[8192],  tid);
    stage_half(Bm, K, col0 + 128, 0,  &lds[12288], tid);
    stage_half(A,  K, row0,       BK, &lds[16384 + 0],     tid);
    stage_half(A,  K, row0 + 128, BK, &lds[16384 + 4096],  tid);
    stage_half(Bm, K, col0,       BK, &lds[16384 + 8192],  tid);
    stage_half(Bm, K, col0 + 128, BK, &lds[16384 + 12288], tid);
    asm volatile("s_waitcnt vmcnt(4)" ::: "memory");   // tile 0 landed
    asm volatile("s_barrier" ::: "memory");

    for (int t = 0; t < NT; ++t) {
        const int cur = (t & 3) * 16384;
        short8 af[4], bfr[4];
        // ---- phase A: A frags fi 0-3 + all B frags; stage A halves of t+2 ----
        #pragma unroll
        for (int fi = 0; fi < 4; ++fi)
            af[fi] = *reinterpret_cast<const short8*>(&lds[cur + arow_s + fi * 512]);
        #pragma unroll
        for (int fj = 0; fj < 4; ++fj)
            bfr[fj] = *reinterpret_cast<const short8*>(&lds[cur + brow_s + fj * 512]);
        if (t + 2 < NT) {
            const int nb = ((t + 2) & 3) * 16384;
            stage_half(A, K, row0,       (t + 2) * BK, &lds[nb],        tid);
            stage_half(A, K, row0 + 128, (t + 2) * BK, &lds[nb + 4096], tid);
        }
        asm volatile("s_barrier" ::: "memory");
        __builtin_amdgcn_s_setprio(1);
        #pragma unroll
        for (int fi = 0; fi < 4; ++fi)
            #pragma unroll
            for (int fj = 0; fj < 4; ++fj)
                acc[fi][fj] = __builtin_amdgcn_mfma_f32_16x16x32_bf16(
                    af[fi], bfr[fj], acc[fi][fj], 0, 0, 0);
        __builtin_amdgcn_s_setprio(0);
        asm volatile("s_barrier" ::: "memory");
        // ---- phase B: A frags fi 4-7; stage B halves of t+2 ----
        #pragma unroll
        for (int fi = 0; fi < 4; ++fi)
            af[fi] = *reinterpret_cast<const short8*>(
                &lds[cur + arow_s + (fi + 4) * 512]);
        if (t + 2 < NT) {
            const int nb = ((t + 2) & 3) * 16384 + 8192;
            stage_half(Bm, K, col0,       (t + 2) * BK, &lds[nb],        tid);
            stage_half(Bm, K, col0 + 128, (t + 2) * BK, &lds[nb + 4096], tid);
        }
        asm volatile("s_barrier" ::: "memory");
        __builtin_amdgcn_s_setprio(1);
        #pragma unroll
        for (int fi = 0; fi < 4; ++fi)
            #pragma unroll
            for (int fj = 0; fj < 4; ++fj)
                acc[fi + 4][fj] = __builtin_amdgcn_mfma_f32_16x16x32_bf16(
                    af[fi], bfr[fj], acc[fi + 4][fj], 0, 0, 0);
        __builtin_amdgcn_s_setprio(0);
        if (t + 1 < NT) {
            // gate tile t+1's data: only t+2's 4 stage-loads may stay in flight
            if (t + 2 < NT) asm volatile("s_waitcnt vmcnt(4)" ::: "memory");
            else            asm volatile("s_waitcnt vmcnt(0)" ::: "memory");
        }
        asm volatile("s_barrier" ::: "memory");
    }

    // epilogue
    #pragma unroll
    for (int fi = 0; fi < 8; ++fi) {
        #pragma unroll
        for (int fj = 0; fj < 4; ++fj) {
            #pragma unroll
            for (int q = 0; q < 4; ++q) {
                int m = row0 + wm * 128 + fi * 16 + kq * 4 + q;
                int n = col0 + wn * 64 + fj * 16 + l15;
                float v = acc[fi][fj][q];
                if (MODE == 0) {
                    C[(size_t)m * N + n] = v + bias0[n] + bias1[n];
                } else {
                    if (n < N) {
                        int t = m >> 7, b = m & 127;
                        C[(size_t)b * (Tt * Vv) + (size_t)t * Vv + n] = v + bias0[n];
                    }
                }
            }
        }
    }
}

// ---------------------------------------------------------------------------
// Rotated h-gather (v11, proven +17us): per-WG compile-time rotation of
// load+MFMA order spreads first-touch L3 line fetches across the XCD.
// ---------------------------------------------------------------------------
template<int ROT>
__device__ __forceinline__ void gate_mfma(
    const unsigned short* __restrict__ hprev,
    const unsigned short* __restrict__ Wl,
    int row0, int wave, int l15, int kq,
    floatx4 (&acc)[2][4])
{
    const short8* ar0 = reinterpret_cast<const short8*>(
        hprev + (size_t)(row0 + l15) * Hh) + wave * 32 + kq;
    const short8* ar1 = reinterpret_cast<const short8*>(
        hprev + (size_t)(row0 + 16 + l15) * Hh) + wave * 32 + kq;
    short8 a0[8], a1[8];
    #pragma unroll
    for (int ks = 0; ks < 8; ++ks) {
        const int j = (ks + ROT) & 7;
        a0[ks] = ar0[j * 4];
        a1[ks] = ar1[j * 4];
    }
    #pragma unroll
    for (int ks = 0; ks < 8; ++ks) {
        const int j = (ks + ROT) & 7;
        const short8* bp = reinterpret_cast<const short8*>(
            &Wl[((wave * 32 + j * 4 + kq) * 64 + l15) * 8]);
        acc[0][0] = __builtin_amdgcn_mfma_f32_16x16x32_bf16(
            a0[ks], bp[0], acc[0][0], 0, 0, 0);
        acc[0][1] = __builtin_amdgcn_mfma_f32_16x16x32_bf16(
            a0[ks], bp[16], acc[0][1], 0, 0, 0);
        acc[0][2] = __builtin_amdgcn_mfma_f32_16x16x32_bf16(
            a0[ks], bp[32], acc[0][2], 0, 0, 0);
        acc[0][3] = __builtin_amdgcn_mfma_f32_16x16x32_bf16(
            a0[ks], bp[48], acc[0][3], 0, 0, 0);
    }
    #pragma unroll
    for (int ks = 0; ks < 8; ++ks) {
        const int j = (ks + ROT) & 7;
        const short8* bp = reinterpret_cast<const short8*>(
            &Wl[((wave * 32 + j * 4 + kq) * 64 + l15) * 8]);
        acc[1][0] = __builtin_amdgcn_mfma_f32_16x16x32_bf16(
            a1[ks], bp[0], acc[1][0], 0, 0, 0);
        acc[1][1] = __builtin_amdgcn_mfma_f32_16x16x32_bf16(
            a1[ks], bp[16], acc[1][1], 0, 0, 0);
        acc[1][2] = __builtin_amdgcn_mfma_f32_16x16x32_bf16(
            a1[ks], bp[32], acc[1][2], 0, 0, 0);
        acc[1][3] = __builtin_amdgcn_mfma_f32_16x16x32_bf16(
            a1[ks], bp[48], acc[1][3], 0, 0, 0);
    }
}

// ---------------------------------------------------------------------------
// Persistent LSTM recurrence, v12: per-wave elastic sync.
// 256 WGs (all 256 CUs), 4 cohorts x 64 WGs, split-K waves, rotated gather.
//
// v12 vs v11 (346 us, 5.40 us/step): 3 full-WG joins/step -> 2, and the
// ack+poll+gather chain moves OUTSIDE all joins:
//  - Per-wave poll: wave w consumes h cols [w*256,+256) produced by counter
//    groups {2w, 2w+1} only. All 64 lanes poll the 2 counters uniformly
//    (need = 32t: 8 WGs x 4 waves x t incs). Post-poll __syncthreads deleted.
//  - Per-wave inc: each wave waits vmcnt(8) for ITS h stores, lane0 incs the
//    WG counter. End-of-step s_barrier deleted.
//  - Redsum epochs separated by one raw s_barrier placed right after the
//    redsum read (all epoch-t reads before it; all epoch-t+1 writes after).
//  - Correctness (first-passer induction): any step-(t+1) inc follows both
//    intra-WG joins of step t+1 => all 4 waves passed poll(t+1), jointly
//    covering all 8 groups >= 32t; at the first such inc all contributors
//    <= t, so every counter = 32t exactly => whole cohort (incl. store
//    acks) completed step t. No speculative h reads (v9 lesson).
// ---------------------------------------------------------------------------
__global__ __launch_bounds__(256)
void lstm_persist(const unsigned short* __restrict__ whhb, // [4096][1024] bf16
                  const float* __restrict__ xg,            // [64*128][4096] f32
                  unsigned short* __restrict__ hsb,        // [64][128][1024] bf16
                  unsigned* __restrict__ flags) {          // 32 ctrs, 64B stride
    __shared__ unsigned short Wlds[64 * Hh];        // 128 KB
    __shared__ float redsum[8 * 3 * 4 * 64];        // 24 KB  [c][slot][nb][lane]
    const int tid  = threadIdx.x;
    const int w    = blockIdx.x;
    const int wg_m = w & 3;        // row cohort: rows [wg_m*32, +32)
    const int wg_n = w >> 2;       // hcol slice (0..63)
    const int wave = tid >> 6;
    const int lane = tid & 63;
    const int l15  = lane & 15;
    const int kq   = lane >> 4;

    for (int i = 0; i < 32; ++i) {
        int e8 = i * 256 + tid;
        int q = e8 >> 6, gc = e8 & 63;
        int grow = (gc >> 4) * Hh + wg_n * 16 + (gc & 15);
        short8 v = *reinterpret_cast<const short8*>(
            whhb + (size_t)grow * Hh + q * 8);
        *reinterpret_cast<short8*>(&Wlds[(q * 64 + gc) * 8]) = v;
    }
    __syncthreads();

    const int row0 = wg_m * 32;
    const int hcol = wg_n * 16 + l15;
    const int lrA = (wave >> 1) * 16 + kq * 4 + ((wave & 1) * 2);
    const int lrB = lrA + 1;
    const int rotsel = (wg_n >> 1) & 3;   // cycles 0..3 within an XCD
    unsigned* myctr = flags + (size_t)(wg_m * 8 + (wg_n >> 3)) * 16;
    const unsigned* pollc = flags + (size_t)(wg_m * 8 + wave * 2) * 16;
    float cell0 = 0.f, cell1 = 0.f;

    float xa[2][4], xb[2][4];
    {
        const float* xrA = xg + (size_t)(row0 + lrA) * G + wg_n * 16 + l15;
        #pragma unroll
        for (int nb = 0; nb < 4; ++nb) {
            xa[0][nb] = xrA[nb * Hh];
            xa[1][nb] = xrA[G + nb * Hh];
        }
    }

#define WRC(W_, C_)                                                            \
    if (((C_) >> 1) != (W_)) {                                                 \
        _Pragma("unroll")                                                      \
        for (int nb = 0; nb < 4; ++nb)                                         \
            redsum[((C_) * 3 + (((W_) > ((C_) >> 1)) ? (W_)-1 : (W_))) * 256   \
                   + nb * 64 + lane] = acc[(C_) >> 2][nb][(C_) & 3];           \
    }

#define SPILL(W_)                                                              \
    do {                                                                       \
        _Pragma("unroll")                                                      \
        for (int nb = 0; nb < 4; ++nb) {                                       \
            own0[nb] = acc[(2 * (W_)) >> 2][nb][(2 * (W_)) & 3];               \
            own1[nb] = acc[(2 * (W_) + 1) >> 2][nb][(2 * (W_) + 1) & 3];       \
        }                                                                      \
        WRC(W_, 0); WRC(W_, 1); WRC(W_, 2); WRC(W_, 3);                        \
        WRC(W_, 4); WRC(W_, 5); WRC(W_, 6); WRC(W_, 7);                        \
    } while (0)

#define LSTM_STEP(T, XC, XN)                                                   \
    do {                                                                       \
        const int t_ = (T);                                                    \
        floatx4 acc[2][4];                                                     \
        _Pragma("unroll")                                                      \
        for (int i = 0; i < 2; ++i)                                            \
            _Pragma("unroll")                                                  \
            for (int j = 0; j < 4; ++j) acc[i][j] = (floatx4)0.f;              \
        if (t_ > 0) {                                                          \
            /* per-wave poll: only this wave's 2 producer groups */            \
            unsigned need = 32u * (unsigned)t_;                                \
            while (__hip_atomic_load(pollc, __ATOMIC_RELAXED,                  \
                                     __HIP_MEMORY_SCOPE_AGENT) < need          \
                || __hip_atomic_load(pollc + 16, __ATOMIC_RELAXED,             \
                                     __HIP_MEMORY_SCOPE_AGENT) < need)         \
                __builtin_amdgcn_s_sleep(1);                                   \
            asm volatile("" ::: "memory");                                     \
            const unsigned short* hprev = hsb + (size_t)(t_ - 1) * (Bb * Hh);  \
            if (rotsel == 0)                                                   \
                gate_mfma<0>(hprev, Wlds, row0, wave, l15, kq, acc);           \
            else if (rotsel == 1)                                              \
                gate_mfma<2>(hprev, Wlds, row0, wave, l15, kq, acc);           \
            else if (rotsel == 2)                                              \
                gate_mfma<4>(hprev, Wlds, row0, wave, l15, kq, acc);           \
            else                                                               \
                gate_mfma<6>(hprev, Wlds, row0, wave, l15, kq, acc);           \
        }                                                                      \
        float own0[4], own1[4];                                                \
        if (wave == 0)      SPILL(0);                                          \
        else if (wave == 1) SPILL(1);                                          \
        else if (wave == 2) SPILL(2);                                          \
        else                SPILL(3);                                          \
        __syncthreads();   /* join 1: redsum writes visible */                 \
        float gA[4], gB[4];                                                    \
        {                                                                      \
            const int cA = wave * 2;                                           \
            _Pragma("unroll")                                                  \
            for (int nb = 0; nb < 4; ++nb) {                                   \
                int bA = (cA * 3) * 256 + nb * 64 + lane;                      \
                gA[nb] = own0[nb] + redsum[bA] + redsum[bA + 256]              \
                       + redsum[bA + 512] + XC[0][nb];                         \
                int bB = ((cA + 1) * 3) * 256 + nb * 64 + lane;                \
                gB[nb] = own1[nb] + redsum[bB] + redsum[bB + 256]              \
                       + redsum[bB + 512] + XC[1][nb];                         \
            }                                                                  \
        }                                                                      \
        /* join 2: all epoch-t redsum reads done; epoch t+1 writes follow */   \
        __builtin_amdgcn_s_barrier();                                          \
        unsigned short* ht = hsb + (size_t)t_ * (Bb * Hh);                     \
        {                                                                      \
            float si = sigmoid_fast(gA[0]);                                    \
            float sf = sigmoid_fast(gA[1]);                                    \
            float tg = tanh_fast(gA[2]);                                       \
            float so = sigmoid_fast(gA[3]);                                    \
            float cn = sf * cell0 + si * tg;                                   \
            cell0 = cn;                                                        \
            float h = so * tanh_fast(cn);                                      \
            __hip_atomic_store(&ht[(size_t)(row0 + lrA) * Hh + hcol], f2bf(h), \
                               __ATOMIC_RELAXED, __HIP_MEMORY_SCOPE_AGENT);    \
        }                                                                      \
        {                                                                      \
            float si = sigmoid_fast(gB[0]);                                    \
            float sf = sigmoid_fast(gB[1]);                                    \
            float tg = tanh_fast(gB[2]);                                       \
            float so = sigmoid_fast(gB[3]);                                    \
            float cn = sf * cell1 + si * tg;                                   \
            cell1 = cn;                                                        \
            float h = so * tanh_fast(cn);                                      \
            __hip_atomic_store(&ht[(size_t)(row0 + lrB) * Hh + hcol], f2bf(h), \
                               __ATOMIC_RELAXED, __HIP_MEMORY_SCOPE_AGENT);    \
        }                                                                      \
        __builtin_amdgcn_sched_barrier(0);                                     \
        if (t_ + 1 < Tt) {   /* xg prefetch: YOUNGEST VMEM (after stores) */   \
            const float* xrA = xg + (size_t)(t_ + 1) * (Bb * G)                \
                + (size_t)(row0 + lrA) * G + wg_n * 16 + l15;                  \
            _Pragma("unroll")                                                  \
            for (int nb = 0; nb < 4; ++nb) {                                   \
                XN[0][nb] = xrA[nb * Hh];                                      \
                XN[1][nb] = xrA[G + nb * Hh];                                  \
            }                                                                  \
        }                                                                      \
        __builtin_amdgcn_sched_barrier(0);                                     \
        if (t_ < Tt - 1) {                                                     \
            /* per-wave: 2 h stores (oldest) + 8 xg loads outstanding */       \
            asm volatile("s_waitcnt vmcnt(8)" ::: "memory");                   \
            __builtin_amdgcn_sched_barrier(0);                                 \
            if (lane == 0)                                                     \
                __hip_atomic_fetch_add(myctr, 1u, __ATOMIC_RELAXED,            \
                                       __HIP_MEMORY_SCOPE_AGENT);              \
        }                                                                      \
    } while (0)

    for (int tt = 0; tt < Tt; tt += 2) {
        LSTM_STEP(tt,     xa, xb);
        LSTM_STEP(tt + 1, xb, xa);
    }
#undef LSTM_STEP
#undef SPILL
#undef WRC
}

// ---------------------------------------------------------------------------
extern "C" void kernel_launch(void* const* d_in, const int* in_sizes, int n_in,
                              void* d_out, int out_size, void* d_ws, size_t ws_size,
                              hipStream_t stream) {
    const float* features = (const float*)d_in[0];
    const int*   captions = (const int*)d_in[1];
    const float* embed_W  = (const float*)d_in[2];
    const float* W_ih     = (const float*)d_in[3];
    const float* W_hh     = (const float*)d_in[4];
    const float* b_ih     = (const float*)d_in[5];
    const float* b_hh     = (const float*)d_in[6];
    const float* fc_W     = (const float*)d_in[7];
    const float* fc_b     = (const float*)d_in[8];
    float* out = (float*)d_out;

    unsigned short* xsb  = (unsigned short*)d_ws;          // [8192][512]
    unsigned short* wihb = xsb  + (size_t)Tt * Bb * Ee;    // [4096][512]
    unsigned short* whhb = wihb + (size_t)G * Ee;          // [4096][1024]
    unsigned short* fcwb = whhb + (size_t)G * Hh;          // [10240][1024]
    unsigned short* hsb  = fcwb + (size_t)Vpad * Hh;       // [64][128][1024]
    float* xg = (float*)(hsb + (size_t)Tt * Bb * Hh);      // [8192][4096]
    unsigned* flags = (unsigned*)(xg + (size_t)Tt * Bb * G); // 32 ctrs, 64B stride

    (void)hipMemsetAsync(flags, 0, 128 * 32 * sizeof(unsigned), stream);

    // 1) weight conversions + input gather
    cvt_bf16<<<(G * Ee / 8) / 256, 256, 0, stream>>>(W_ih, wihb, G * Ee, G * Ee);
    cvt_bf16<<<(G * Hh / 8) / 256, 256, 0, stream>>>(W_hh, whhb, G * Hh, G * Hh);
    cvt_bf16<<<(Vpad * Hh / 8) / 256, 256, 0, stream>>>(fc_W, fcwb, Vv * Hh, Vpad * Hh);
    gather_xs<<<(Tt * Bb * (Ee / 8)) / 256, 256, 0, stream>>>(
        features, captions, embed_W, xsb);

    // 2) x_gates = xs @ W_ih^T + b_ih + b_hh   (M=8192, N=4096, K=512)
    {
        dim3 grid(8192 / 256, G / 256);   // 32 x 16 = 512 wgs (%8 == 0)
        gemm256<0><<<grid, 512, 0, stream>>>(
            xsb, wihb, 8192, G, Ee, b_ih, b_hh, xg);
    }

    // 3) persistent LSTM recurrence (one launch, 64 steps, all 256 CUs)
    lstm_persist<<<256, 256, 0, stream>>>(whhb, xg, hsb, flags);

    // 4) out[b,t,v] = hs @ fc_W^T + fc_b   (M=8192, N=10000(pad 10240), K=1024)
    {
        dim3 grid(8192 / 256, Vpad / 256);  // 32 x 40 = 1280 wgs (%8 == 0)
        gemm256<2><<<grid, 512, 0, stream>>>(
            hsb, fcwb, 8192, Vv, Hh, fc_b, nullptr, out);
    }
}

// Round 9
// 663.580 us; speedup vs baseline: 1.2648x; 1.2648x over previous
//
#include <hip/hip_runtime.h>
#include <math.h>

// Problem constants
static constexpr int Bb = 128;    // batch
static constexpr int Tt = 64;     // seq len
static constexpr int Ee = 512;    // embed dim
static constexpr int Hh = 1024;   // hidden
static constexpr int Vv = 10000;  // vocab
static constexpr int G  = 4 * Hh; // 4096 gates
static constexpr int Vpad = 10240; // 40*256, zero-padded vocab rows (256-tiles)

typedef __attribute__((ext_vector_type(8))) short short8;
typedef __attribute__((ext_vector_type(4))) float floatx4;

__device__ __forceinline__ unsigned short f2bf(float f) {
    unsigned u = __float_as_uint(f);
    return (unsigned short)((u + 0x7fffu + ((u >> 16) & 1u)) >> 16);  // RNE
}

__device__ __forceinline__ void gload16(const void* g, void* l) {
    __builtin_amdgcn_global_load_lds(
        (const __attribute__((address_space(1))) void*)g,
        (__attribute__((address_space(3))) void*)l, 16, 0, 0);
}

// fast transcendentals (v_exp_f32 + v_rcp_f32; ~1e-6 rel err, far below bf16)
__device__ __forceinline__ float sigmoid_fast(float x) {
    return __builtin_amdgcn_rcpf(1.f + __expf(-x));
}
__device__ __forceinline__ float tanh_fast(float x) {
    float e = __expf(-2.f * fabsf(x));
    float t = (1.f - e) * __builtin_amdgcn_rcpf(1.f + e);
    return copysignf(t, x);
}

// ---------------------------------------------------------------------------
// f32 -> bf16 convert, with zero-padding up to npad elements
// ---------------------------------------------------------------------------
__global__ __launch_bounds__(256)
void cvt_bf16(const float* __restrict__ s, unsigned short* __restrict__ d,
              int n, int npad) {
    int i8 = (blockIdx.x * 256 + threadIdx.x) * 8;
    if (i8 >= npad) return;
    short8 v;
    #pragma unroll
    for (int j = 0; j < 8; ++j) {
        int e = i8 + j;
        float f = (e < n) ? s[e] : 0.f;
        v[j] = (short)f2bf(f);
    }
    *reinterpret_cast<short8*>(d + i8) = v;
}

// ---------------------------------------------------------------------------
// Gather xs[t*B+b, :] = bf16( t==0 ? features[b,:] : embed_W[captions[b,t],:] )
// ---------------------------------------------------------------------------
__global__ __launch_bounds__(256)
void gather_xs(const float* __restrict__ features,
               const int* __restrict__ captions,
               const float* __restrict__ embed_W,
               unsigned short* __restrict__ xs) {
    int idx = blockIdx.x * 256 + threadIdx.x;   // T*B*(E/8)
    int m  = idx >> 6;                          // row, E/8 = 64 chunks per row
    int c8 = (idx & 63) * 8;
    int t = m >> 7;                             // m / B
    int b = m & 127;                            // m % B
    const float* src;
    if (t == 0) {
        src = features + (size_t)b * Ee + c8;
    } else {
        int tok = captions[(size_t)b * Tt + t];
        src = embed_W + (size_t)tok * Ee + c8;
    }
    short8 v;
    #pragma unroll
    for (int j = 0; j < 8; ++j) v[j] = (short)f2bf(src[j]);
    *reinterpret_cast<short8*>(xs + (size_t)m * Ee + c8) = v;
}

// ---------------------------------------------------------------------------
// 256x256-tile bf16 MFMA GEMM, BK=32, 4-deep circular LDS pipeline.
//   (unchanged from v10 — proven passing)
// ---------------------------------------------------------------------------
__device__ __forceinline__ void stage_half(
    const unsigned short* __restrict__ Gsrc, int Kdim, int rowbase, int k0,
    unsigned short* ldsbase, int tid) {
    // one 16B load per thread covers the 8 KB half-tile (128 rows x 32 k)
    int e = tid * 16;                     // byte offset in half-tile
    int r = e >> 6;                       // row 0..127
    int c = e & 63;                       // byte in row (0/16/32/48)
    int c_log = c ^ ((r & 3) << 4);       // inverse-swizzled source column
    gload16(Gsrc + (size_t)(rowbase + r) * Kdim + k0 + (c_log >> 1),
            ldsbase + tid * 8);
}

template<int MODE>
__global__ __launch_bounds__(512, 2)
void gemm256(const unsigned short* __restrict__ A,
             const unsigned short* __restrict__ Bm,
             int M, int N, int K,
             const float* __restrict__ bias0, const float* __restrict__ bias1,
             float* __restrict__ C) {
    constexpr int BK = 32;
    __shared__ unsigned short lds[4 * 2 * 256 * BK];   // 128 KB

    const int nwg = gridDim.x * gridDim.y;
    const int flat = blockIdx.y * gridDim.x + blockIdx.x;
    const int tix = (flat & 7) * (nwg >> 3) + (flat >> 3);
    const int bx = tix % gridDim.x;
    const int by = tix / gridDim.x;

    const int tid  = threadIdx.x;
    const int wid  = tid >> 6;      // 0..7
    const int lane = tid & 63;
    const int wm = wid >> 2;        // 0..1  (M half)
    const int wn = wid & 3;         // 0..3  (N quarter)
    const int row0 = bx * 256;
    const int col0 = by * 256;
    const int l15 = lane & 15;
    const int kq  = lane >> 4;

    const int NT = K / BK;

    // per-thread ds_read bases (shorts); swizzled slot kq ^ (row&3), row&3==l15&3
    const int swz = (kq ^ (l15 & 3)) * 8;
    const int arow_s = wm * 4096 + l15 * 32 + swz;
    const int brow_s = 8192 + (wn >> 1) * 4096 + ((wn & 1) * 64 + l15) * 32 + swz;

    floatx4 acc[8][4];
    #pragma unroll
    for (int i = 0; i < 8; ++i)
        #pragma unroll
        for (int j = 0; j < 4; ++j) acc[i][j] = (floatx4)0.f;

    // prologue: stage tiles 0 and 1 (4 half-tiles each)
    stage_half(A,  K, row0,       0,  &lds[0],     tid);
    stage_half(A,  K, row0 + 128, 0,  &lds[4096],  tid);
    stage_half(Bm, K, col0,       0,  &lds[8192],  tid);
    stage_half(Bm, K, col0 + 128, 0,  &lds[12288], tid);
    stage_half(A,  K, row0,       BK, &lds[16384 + 0],     tid);
    stage_half(A,  K, row0 + 128, BK, &lds[16384 + 4096],  tid);
    stage_half(Bm, K, col0,       BK, &lds[16384 + 8192],  tid);
    stage_half(Bm, K, col0 + 128, BK, &lds[16384 + 12288], tid);
    asm volatile("s_waitcnt vmcnt(4)" ::: "memory");   // tile 0 landed
    asm volatile("s_barrier" ::: "memory");

    for (int t = 0; t < NT; ++t) {
        const int cur = (t & 3) * 16384;
        short8 af[4], bfr[4];
        // ---- phase A: A frags fi 0-3 + all B frags; stage A halves of t+2 ----
        #pragma unroll
        for (int fi = 0; fi < 4; ++fi)
            af[fi] = *reinterpret_cast<const short8*>(&lds[cur + arow_s + fi * 512]);
        #pragma unroll
        for (int fj = 0; fj < 4; ++fj)
            bfr[fj] = *reinterpret_cast<const short8*>(&lds[cur + brow_s + fj * 512]);
        if (t + 2 < NT) {
            const int nb = ((t + 2) & 3) * 16384;
            stage_half(A, K, row0,       (t + 2) * BK, &lds[nb],        tid);
            stage_half(A, K, row0 + 128, (t + 2) * BK, &lds[nb + 4096], tid);
        }
        asm volatile("s_barrier" ::: "memory");
        __builtin_amdgcn_s_setprio(1);
        #pragma unroll
        for (int fi = 0; fi < 4; ++fi)
            #pragma unroll
            for (int fj = 0; fj < 4; ++fj)
                acc[fi][fj] = __builtin_amdgcn_mfma_f32_16x16x32_bf16(
                    af[fi], bfr[fj], acc[fi][fj], 0, 0, 0);
        __builtin_amdgcn_s_setprio(0);
        asm volatile("s_barrier" ::: "memory");
        // ---- phase B: A frags fi 4-7; stage B halves of t+2 ----
        #pragma unroll
        for (int fi = 0; fi < 4; ++fi)
            af[fi] = *reinterpret_cast<const short8*>(
                &lds[cur + arow_s + (fi + 4) * 512]);
        if (t + 2 < NT) {
            const int nb = ((t + 2) & 3) * 16384 + 8192;
            stage_half(Bm, K, col0,       (t + 2) * BK, &lds[nb],        tid);
            stage_half(Bm, K, col0 + 128, (t + 2) * BK, &lds[nb + 4096], tid);
        }
        asm volatile("s_barrier" ::: "memory");
        __builtin_amdgcn_s_setprio(1);
        #pragma unroll
        for (int fi = 0; fi < 4; ++fi)
            #pragma unroll
            for (int fj = 0; fj < 4; ++fj)
                acc[fi + 4][fj] = __builtin_amdgcn_mfma_f32_16x16x32_bf16(
                    af[fi], bfr[fj], acc[fi + 4][fj], 0, 0, 0);
        __builtin_amdgcn_s_setprio(0);
        if (t + 1 < NT) {
            // gate tile t+1's data: only t+2's 4 stage-loads may stay in flight
            if (t + 2 < NT) asm volatile("s_waitcnt vmcnt(4)" ::: "memory");
            else            asm volatile("s_waitcnt vmcnt(0)" ::: "memory");
        }
        asm volatile("s_barrier" ::: "memory");
    }

    // epilogue
    #pragma unroll
    for (int fi = 0; fi < 8; ++fi) {
        #pragma unroll
        for (int fj = 0; fj < 4; ++fj) {
            #pragma unroll
            for (int q = 0; q < 4; ++q) {
                int m = row0 + wm * 128 + fi * 16 + kq * 4 + q;
                int n = col0 + wn * 64 + fj * 16 + l15;
                float v = acc[fi][fj][q];
                if (MODE == 0) {
                    C[(size_t)m * N + n] = v + bias0[n] + bias1[n];
                } else {
                    if (n < N) {
                        int t = m >> 7, b = m & 127;
                        C[(size_t)b * (Tt * Vv) + (size_t)t * Vv + n] = v + bias0[n];
                    }
                }
            }
        }
    }
}

// ---------------------------------------------------------------------------
// v13 gate MFMA: W operands in REGISTERS (wreg[8][4] short8 = 128 VGPR),
// rotated h-gather (v11, proven). a0/a1 loads rotated per-WG; MFMA pairs
// a0[ks] with wreg[(ks+ROT)&7][nb] — all indices compile-time.
// ---------------------------------------------------------------------------
template<int ROT>
__device__ __forceinline__ void gate_mfma(
    const unsigned short* __restrict__ hprev,
    const short8 (&wreg)[8][4],
    int row0, int wave, int l15, int kq,
    floatx4 (&acc)[2][4])
{
    const short8* ar0 = reinterpret_cast<const short8*>(
        hprev + (size_t)(row0 + l15) * Hh) + wave * 32 + kq;
    const short8* ar1 = reinterpret_cast<const short8*>(
        hprev + (size_t)(row0 + 16 + l15) * Hh) + wave * 32 + kq;
    short8 a0[8], a1[8];
    #pragma unroll
    for (int ks = 0; ks < 8; ++ks) {
        const int j = (ks + ROT) & 7;
        a0[ks] = ar0[j * 4];
        a1[ks] = ar1[j * 4];
    }
    #pragma unroll
    for (int ks = 0; ks < 8; ++ks) {
        const int j = (ks + ROT) & 7;
        acc[0][0] = __builtin_amdgcn_mfma_f32_16x16x32_bf16(
            a0[ks], wreg[j][0], acc[0][0], 0, 0, 0);
        acc[0][1] = __builtin_amdgcn_mfma_f32_16x16x32_bf16(
            a0[ks], wreg[j][1], acc[0][1], 0, 0, 0);
        acc[0][2] = __builtin_amdgcn_mfma_f32_16x16x32_bf16(
            a0[ks], wreg[j][2], acc[0][2], 0, 0, 0);
        acc[0][3] = __builtin_amdgcn_mfma_f32_16x16x32_bf16(
            a0[ks], wreg[j][3], acc[0][3], 0, 0, 0);
    }
    #pragma unroll
    for (int ks = 0; ks < 8; ++ks) {
        const int j = (ks + ROT) & 7;
        acc[1][0] = __builtin_amdgcn_mfma_f32_16x16x32_bf16(
            a1[ks], wreg[j][0], acc[1][0], 0, 0, 0);
        acc[1][1] = __builtin_amdgcn_mfma_f32_16x16x32_bf16(
            a1[ks], wreg[j][1], acc[1][1], 0, 0, 0);
        acc[1][2] = __builtin_amdgcn_mfma_f32_16x16x32_bf16(
            a1[ks], wreg[j][2], acc[1][2], 0, 0, 0);
        acc[1][3] = __builtin_amdgcn_mfma_f32_16x16x32_bf16(
            a1[ks], wreg[j][3], acc[1][3], 0, 0, 0);
    }
}

// ---------------------------------------------------------------------------
// Persistent LSTM recurrence, v13: v11 sync (proven) + W-in-registers.
// 256 WGs (all 256 CUs), 4 cohorts x 64 WGs, split-K waves, rotated gather.
//
// v12 post-mortem: per-wave elastic sync REGRESSED (508us) — 4x counter
// atomics + 1024 spinning waves recreated the v5 poll-storm contention.
// Sync reverted to v11's counter tree (tid<8 poll, end-of-step s_barrier,
// tid0 inc). New in v13: the compute phase was LDS-read-bound (256 b128
// reads x ~12cy = ~3000cy/step vs ~1240cy MFMA). W_hh is constant across
// steps and each wave reuses the same 32 B-fragments -> keep W in 128 VGPRs
// (wreg[8][4]), loaded once. LDS drops to redsum 24KB; launch_bounds(256,1)
// lifts the VGPR cap to 512 (1 wave/SIMD, unchanged occupancy).
// ---------------------------------------------------------------------------
__global__ __launch_bounds__(256, 1)
void lstm_persist(const unsigned short* __restrict__ whhb, // [4096][1024] bf16
                  const float* __restrict__ xg,            // [64*128][4096] f32
                  unsigned short* __restrict__ hsb,        // [64][128][1024] bf16
                  unsigned* __restrict__ flags) {          // 32 ctrs, 64B stride
    __shared__ float redsum[8 * 3 * 4 * 64];        // 24 KB  [c][slot][nb][lane]
    const int tid  = threadIdx.x;
    const int w    = blockIdx.x;
    const int wg_m = w & 3;        // row cohort: rows [wg_m*32, +32)
    const int wg_n = w >> 2;       // hcol slice (0..63)
    const int wave = tid >> 6;
    const int lane = tid & 63;
    const int l15  = lane & 15;
    const int kq   = lane >> 4;

    const int row0 = wg_m * 32;
    const int hcol = wg_n * 16 + l15;
    const int lrA = (wave >> 1) * 16 + kq * 4 + ((wave & 1) * 2);
    const int lrB = lrA + 1;
    const int rotsel = (wg_n >> 1) & 3;   // cycles 0..3 within an XCD
    unsigned* myctr = flags + (size_t)(wg_m * 8 + (wg_n >> 3)) * 16;
    float cell0 = 0.f, cell1 = 0.f;

    // W_hh fragments in registers, loaded once (same algebra as old Wlds):
    // wreg[j][nb] = whhb[(nb*1024 + wg_n*16 + l15)*1024 + (wave*32+j*4+kq)*8]
    short8 wreg[8][4];
    {
        const unsigned short* wbase = whhb
            + (size_t)(wg_n * 16 + l15) * Hh + wave * 256 + kq * 8;
        #pragma unroll
        for (int nb = 0; nb < 4; ++nb)
            #pragma unroll
            for (int j = 0; j < 8; ++j)
                wreg[j][nb] = *reinterpret_cast<const short8*>(
                    wbase + (size_t)nb * Hh * Hh + j * 32);
    }

    float xa[2][4], xb[2][4];
    {
        const float* xrA = xg + (size_t)(row0 + lrA) * G + wg_n * 16 + l15;
        #pragma unroll
        for (int nb = 0; nb < 4; ++nb) {
            xa[0][nb] = xrA[nb * Hh];
            xa[1][nb] = xrA[G + nb * Hh];
        }
    }

#define WRC(W_, C_)                                                            \
    if (((C_) >> 1) != (W_)) {                                                 \
        _Pragma("unroll")                                                      \
        for (int nb = 0; nb < 4; ++nb)                                         \
            redsum[((C_) * 3 + (((W_) > ((C_) >> 1)) ? (W_)-1 : (W_))) * 256   \
                   + nb * 64 + lane] = acc[(C_) >> 2][nb][(C_) & 3];           \
    }

#define SPILL(W_)                                                              \
    do {                                                                       \
        _Pragma("unroll")                                                      \
        for (int nb = 0; nb < 4; ++nb) {                                       \
            own0[nb] = acc[(2 * (W_)) >> 2][nb][(2 * (W_)) & 3];               \
            own1[nb] = acc[(2 * (W_) + 1) >> 2][nb][(2 * (W_) + 1) & 3];       \
        }                                                                      \
        WRC(W_, 0); WRC(W_, 1); WRC(W_, 2); WRC(W_, 3);                        \
        WRC(W_, 4); WRC(W_, 5); WRC(W_, 6); WRC(W_, 7);                        \
    } while (0)

#define LSTM_STEP(T, XC, XN)                                                   \
    do {                                                                       \
        const int t_ = (T);                                                    \
        floatx4 acc[2][4];                                                     \
        _Pragma("unroll")                                                      \
        for (int i = 0; i < 2; ++i)                                            \
            _Pragma("unroll")                                                  \
            for (int j = 0; j < 4; ++j) acc[i][j] = (floatx4)0.f;              \
        if (t_ > 0) {                                                          \
            if (tid < 8) {                                                     \
                const unsigned* fl = flags + (size_t)(wg_m * 8 + tid) * 16;    \
                unsigned need = 8u * (unsigned)t_;                             \
                while (__hip_atomic_load(fl, __ATOMIC_RELAXED,                 \
                                         __HIP_MEMORY_SCOPE_AGENT) < need)     \
                    __builtin_amdgcn_s_sleep(1);                               \
            }                                                                  \
            __syncthreads();                                                   \
            asm volatile("" ::: "memory");                                     \
            const unsigned short* hprev = hsb + (size_t)(t_ - 1) * (Bb * Hh);  \
            if (rotsel == 0)                                                   \
                gate_mfma<0>(hprev, wreg, row0, wave, l15, kq, acc);           \
            else if (rotsel == 1)                                              \
                gate_mfma<2>(hprev, wreg, row0, wave, l15, kq, acc);           \
            else if (rotsel == 2)                                              \
                gate_mfma<4>(hprev, wreg, row0, wave, l15, kq, acc);           \
            else                                                               \
                gate_mfma<6>(hprev, wreg, row0, wave, l15, kq, acc);           \
        }                                                                      \
        float own0[4], own1[4];                                                \
        if (wave == 0)      SPILL(0);                                          \
        else if (wave == 1) SPILL(1);                                          \
        else if (wave == 2) SPILL(2);                                          \
        else                SPILL(3);                                          \
        __syncthreads();                                                       \
        float gA[4], gB[4];                                                    \
        {                                                                      \
            const int cA = wave * 2;                                           \
            _Pragma("unroll")                                                  \
            for (int nb = 0; nb < 4; ++nb) {                                   \
                int bA = (cA * 3) * 256 + nb * 64 + lane;                      \
                gA[nb] = own0[nb] + redsum[bA] + redsum[bA + 256]              \
                       + redsum[bA + 512] + XC[0][nb];                         \
                int bB = ((cA + 1) * 3) * 256 + nb * 64 + lane;                \
                gB[nb] = own1[nb] + redsum[bB] + redsum[bB + 256]              \
                       + redsum[bB + 512] + XC[1][nb];                         \
            }                                                                  \
        }                                                                      \
        unsigned short* ht = hsb + (size_t)t_ * (Bb * Hh);                     \
        {                                                                      \
            float si = sigmoid_fast(gA[0]);                                    \
            float sf = sigmoid_fast(gA[1]);                                    \
            float tg = tanh_fast(gA[2]);                                       \
            float so = sigmoid_fast(gA[3]);                                    \
            float cn = sf * cell0 + si * tg;                                   \
            cell0 = cn;                                                        \
            float h = so * tanh_fast(cn);                                      \
            __hip_atomic_store(&ht[(size_t)(row0 + lrA) * Hh + hcol], f2bf(h), \
                               __ATOMIC_RELAXED, __HIP_MEMORY_SCOPE_AGENT);    \
        }                                                                      \
        {                                                                      \
            float si = sigmoid_fast(gB[0]);                                    \
            float sf = sigmoid_fast(gB[1]);                                    \
            float tg = tanh_fast(gB[2]);                                       \
            float so = sigmoid_fast(gB[3]);                                    \
            float cn = sf * cell1 + si * tg;                                   \
            cell1 = cn;                                                        \
            float h = so * tanh_fast(cn);                                      \
            __hip_atomic_store(&ht[(size_t)(row0 + lrB) * Hh + hcol], f2bf(h), \
                               __ATOMIC_RELAXED, __HIP_MEMORY_SCOPE_AGENT);    \
        }                                                                      \
        __builtin_amdgcn_sched_barrier(0);                                     \
        if (t_ + 1 < Tt) {   /* xg prefetch: YOUNGEST VMEM (after stores) */   \
            const float* xrA = xg + (size_t)(t_ + 1) * (Bb * G)                \
                + (size_t)(row0 + lrA) * G + wg_n * 16 + l15;                  \
            _Pragma("unroll")                                                  \
            for (int nb = 0; nb < 4; ++nb) {                                   \
                XN[0][nb] = xrA[nb * Hh];                                      \
                XN[1][nb] = xrA[G + nb * Hh];                                  \
            }                                                                  \
        }                                                                      \
        __builtin_amdgcn_sched_barrier(0);                                     \
        if (t_ < Tt - 1) {                                                     \
            /* 2 h stores (oldest) + 8 xg loads outstanding: wait stores */    \
            asm volatile("s_waitcnt vmcnt(8)" ::: "memory");                   \
            __builtin_amdgcn_sched_barrier(0);                                 \
            __builtin_amdgcn_s_barrier();                                      \
            __builtin_amdgcn_sched_barrier(0);                                 \
            if (tid == 0)                                                      \
                __hip_atomic_fetch_add(myctr, 1u, __ATOMIC_RELAXED,            \
                                       __HIP_MEMORY_SCOPE_AGENT);              \
        }                                                                      \
    } while (0)

    for (int tt = 0; tt < Tt; tt += 2) {
        LSTM_STEP(tt,     xa, xb);
        LSTM_STEP(tt + 1, xb, xa);
    }
#undef LSTM_STEP
#undef SPILL
#undef WRC
}

// ---------------------------------------------------------------------------
extern "C" void kernel_launch(void* const* d_in, const int* in_sizes, int n_in,
                              void* d_out, int out_size, void* d_ws, size_t ws_size,
                              hipStream_t stream) {
    const float* features = (const float*)d_in[0];
    const int*   captions = (const int*)d_in[1];
    const float* embed_W  = (const float*)d_in[2];
    const float* W_ih     = (const float*)d_in[3];
    const float* W_hh     = (const float*)d_in[4];
    const float* b_ih     = (const float*)d_in[5];
    const float* b_hh     = (const float*)d_in[6];
    const float* fc_W     = (const float*)d_in[7];
    const float* fc_b     = (const float*)d_in[8];
    float* out = (float*)d_out;

    unsigned short* xsb  = (unsigned short*)d_ws;          // [8192][512]
    unsigned short* wihb = xsb  + (size_t)Tt * Bb * Ee;    // [4096][512]
    unsigned short* whhb = wihb + (size_t)G * Ee;          // [4096][1024]
    unsigned short* fcwb = whhb + (size_t)G * Hh;          // [10240][1024]
    unsigned short* hsb  = fcwb + (size_t)Vpad * Hh;       // [64][128][1024]
    float* xg = (float*)(hsb + (size_t)Tt * Bb * Hh);      // [8192][4096]
    unsigned* flags = (unsigned*)(xg + (size_t)Tt * Bb * G); // 32 ctrs, 64B stride

    (void)hipMemsetAsync(flags, 0, 128 * 32 * sizeof(unsigned), stream);

    // 1) weight conversions + input gather
    cvt_bf16<<<(G * Ee / 8) / 256, 256, 0, stream>>>(W_ih, wihb, G * Ee, G * Ee);
    cvt_bf16<<<(G * Hh / 8) / 256, 256, 0, stream>>>(W_hh, whhb, G * Hh, G * Hh);
    cvt_bf16<<<(Vpad * Hh / 8) / 256, 256, 0, stream>>>(fc_W, fcwb, Vv * Hh, Vpad * Hh);
    gather_xs<<<(Tt * Bb * (Ee / 8)) / 256, 256, 0, stream>>>(
        features, captions, embed_W, xsb);

    // 2) x_gates = xs @ W_ih^T + b_ih + b_hh   (M=8192, N=4096, K=512)
    {
        dim3 grid(8192 / 256, G / 256);   // 32 x 16 = 512 wgs (%8 == 0)
        gemm256<0><<<grid, 512, 0, stream>>>(
            xsb, wihb, 8192, G, Ee, b_ih, b_hh, xg);
    }

    // 3) persistent LSTM recurrence (one launch, 64 steps, all 256 CUs)
    lstm_persist<<<256, 256, 0, stream>>>(whhb, xg, hsb, flags);

    // 4) out[b,t,v] = hs @ fc_W^T + fc_b   (M=8192, N=10000(pad 10240), K=1024)
    {
        dim3 grid(8192 / 256, Vpad / 256);  // 32 x 40 = 1280 wgs (%8 == 0)
        gemm256<2><<<grid, 512, 0, stream>>>(
            hsb, fcwb, 8192, Vv, Hh, fc_b, nullptr, out);
    }
}

// Round 11
// 655.019 us; speedup vs baseline: 1.2814x; 1.0131x over previous
//
#include <hip/hip_runtime.h>
#include <math.h>

// Problem constants
static constexpr int Bb = 128;    // batch
static constexpr int Tt = 64;     // seq len
static constexpr int Ee = 512;    // embed dim
static constexpr int Hh = 1024;   // hidden
static constexpr int Vv = 10000;  // vocab
static constexpr int G  = 4 * Hh; // 4096 gates
static constexpr int Vpad = 10240; // 40*256, zero-padded vocab rows (256-tiles)

typedef __attribute__((ext_vector_type(8))) short short8;
typedef __attribute__((ext_vector_type(4))) float floatx4;

__device__ __forceinline__ unsigned short f2bf(float f) {
    unsigned u = __float_as_uint(f);
    return (unsigned short)((u + 0x7fffu + ((u >> 16) & 1u)) >> 16);  // RNE
}

__device__ __forceinline__ void gload16(const void* g, void* l) {
    __builtin_amdgcn_global_load_lds(
        (const __attribute__((address_space(1))) void*)g,
        (__attribute__((address_space(3))) void*)l, 16, 0, 0);
}

// fast transcendentals (v_exp_f32 + v_rcp_f32; ~1e-6 rel err, far below bf16)
__device__ __forceinline__ float sigmoid_fast(float x) {
    return __builtin_amdgcn_rcpf(1.f + __expf(-x));
}
__device__ __forceinline__ float tanh_fast(float x) {
    float e = __expf(-2.f * fabsf(x));
    float t = (1.f - e) * __builtin_amdgcn_rcpf(1.f + e);
    return copysignf(t, x);
}

// ---------------------------------------------------------------------------
// Fused prep: 3x f32->bf16 weight converts + caption/feature gather in ONE
// dispatch (saves 3 kernel launches + stream gaps). Block ranges:
//   [0,1024)      cvt W_ih   (G*Ee elems, no pad)
//   [1024,3072)   cvt W_hh   (G*Hh elems, no pad)
//   [3072,8192)   cvt fc_W   (Vv*Hh elems, zero-pad to Vpad*Hh)
//   [8192,10240)  gather xs
// Each branch is byte-identical logic to the previous standalone kernels.
// ---------------------------------------------------------------------------
__device__ __forceinline__ void cvt8_body(const float* __restrict__ s,
                                          unsigned short* __restrict__ d,
                                          int n, int i8) {
    short8 v;
    #pragma unroll
    for (int j = 0; j < 8; ++j) {
        int e = i8 + j;
        float f = (e < n) ? s[e] : 0.f;
        v[j] = (short)f2bf(f);
    }
    *reinterpret_cast<short8*>(d + i8) = v;
}

__global__ __launch_bounds__(256)
void prep(const float* __restrict__ W_ih, const float* __restrict__ W_hh,
          const float* __restrict__ fc_W, const float* __restrict__ features,
          const int* __restrict__ captions, const float* __restrict__ embed_W,
          unsigned short* __restrict__ wihb, unsigned short* __restrict__ whhb,
          unsigned short* __restrict__ fcwb, unsigned short* __restrict__ xsb) {
    const int blk = blockIdx.x;
    const int tid = threadIdx.x;
    if (blk < 1024) {
        cvt8_body(W_ih, wihb, G * Ee, (blk * 256 + tid) * 8);
    } else if (blk < 3072) {
        cvt8_body(W_hh, whhb, G * Hh, ((blk - 1024) * 256 + tid) * 8);
    } else if (blk < 8192) {
        cvt8_body(fc_W, fcwb, Vv * Hh, ((blk - 3072) * 256 + tid) * 8);
    } else {
        int idx = (blk - 8192) * 256 + tid;     // T*B*(E/8)
        int m  = idx >> 6;                      // row, 64 chunks per row
        int c8 = (idx & 63) * 8;
        int t = m >> 7;                         // m / B
        int b = m & 127;                        // m % B
        const float* src;
        if (t == 0) {
            src = features + (size_t)b * Ee + c8;
        } else {
            int tok = captions[(size_t)b * Tt + t];
            src = embed_W + (size_t)tok * Ee + c8;
        }
        short8 v;
        #pragma unroll
        for (int j = 0; j < 8; ++j) v[j] = (short)f2bf(src[j]);
        *reinterpret_cast<short8*>(xsb + (size_t)m * Ee + c8) = v;
    }
}

// ---------------------------------------------------------------------------
// 256x256-tile bf16 MFMA GEMM, BK=32, 4-deep circular LDS pipeline.
//   (unchanged from v10 — proven passing)
// ---------------------------------------------------------------------------
__device__ __forceinline__ void stage_half(
    const unsigned short* __restrict__ Gsrc, int Kdim, int rowbase, int k0,
    unsigned short* ldsbase, int tid) {
    // one 16B load per thread covers the 8 KB half-tile (128 rows x 32 k)
    int e = tid * 16;                     // byte offset in half-tile
    int r = e >> 6;                       // row 0..127
    int c = e & 63;                       // byte in row (0/16/32/48)
    int c_log = c ^ ((r & 3) << 4);       // inverse-swizzled source column
    gload16(Gsrc + (size_t)(rowbase + r) * Kdim + k0 + (c_log >> 1),
            ldsbase + tid * 8);
}

template<int MODE>
__global__ __launch_bounds__(512, 2)
void gemm256(const unsigned short* __restrict__ A,
             const unsigned short* __restrict__ Bm,
             int M, int N, int K,
             const float* __restrict__ bias0, const float* __restrict__ bias1,
             float* __restrict__ C) {
    constexpr int BK = 32;
    __shared__ unsigned short lds[4 * 2 * 256 * BK];   // 128 KB

    const int nwg = gridDim.x * gridDim.y;
    const int flat = blockIdx.y * gridDim.x + blockIdx.x;
    const int tix = (flat & 7) * (nwg >> 3) + (flat >> 3);
    const int bx = tix % gridDim.x;
    const int by = tix / gridDim.x;

    const int tid  = threadIdx.x;
    const int wid  = tid >> 6;      // 0..7
    const int lane = tid & 63;
    const int wm = wid >> 2;        // 0..1  (M half)
    const int wn = wid & 3;         // 0..3  (N quarter)
    const int row0 = bx * 256;
    const int col0 = by * 256;
    const int l15 = lane & 15;
    const int kq  = lane >> 4;

    const int NT = K / BK;

    // per-thread ds_read bases (shorts); swizzled slot kq ^ (row&3), row&3==l15&3
    const int swz = (kq ^ (l15 & 3)) * 8;
    const int arow_s = wm * 4096 + l15 * 32 + swz;
    const int brow_s = 8192 + (wn >> 1) * 4096 + ((wn & 1) * 64 + l15) * 32 + swz;

    floatx4 acc[8][4];
    #pragma unroll
    for (int i = 0; i < 8; ++i)
        #pragma unroll
        for (int j = 0; j < 4; ++j) acc[i][j] = (floatx4)0.f;

    // prologue: stage tiles 0 and 1 (4 half-tiles each)
    stage_half(A,  K, row0,       0,  &lds[0],     tid);
    stage_half(A,  K, row0 + 128, 0,  &lds[4096],  tid);
    stage_half(Bm, K, col0,       0,  &lds[8192],  tid);
    stage_half(Bm, K, col0 + 128, 0,  &lds[12288], tid);
    stage_half(A,  K, row0,       BK, &lds[16384 + 0],     tid);
    stage_half(A,  K, row0 + 128, BK, &lds[16384 + 4096],  tid);
    stage_half(Bm, K, col0,       BK, &lds[16384 + 8192],  tid);
    stage_half(Bm, K, col0 + 128, BK, &lds[16384 + 12288], tid);
    asm volatile("s_waitcnt vmcnt(4)" ::: "memory");   // tile 0 landed
    asm volatile("s_barrier" ::: "memory");

    for (int t = 0; t < NT; ++t) {
        const int cur = (t & 3) * 16384;
        short8 af[4], bfr[4];
        // ---- phase A: A frags fi 0-3 + all B frags; stage A halves of t+2 ----
        #pragma unroll
        for (int fi = 0; fi < 4; ++fi)
            af[fi] = *reinterpret_cast<const short8*>(&lds[cur + arow_s + fi * 512]);
        #pragma unroll
        for (int fj = 0; fj < 4; ++fj)
            bfr[fj] = *reinterpret_cast<const short8*>(&lds[cur + brow_s + fj * 512]);
        if (t + 2 < NT) {
            const int nb = ((t + 2) & 3) * 16384;
            stage_half(A, K, row0,       (t + 2) * BK, &lds[nb],        tid);
            stage_half(A, K, row0 + 128, (t + 2) * BK, &lds[nb + 4096], tid);
        }
        asm volatile("s_barrier" ::: "memory");
        __builtin_amdgcn_s_setprio(1);
        #pragma unroll
        for (int fi = 0; fi < 4; ++fi)
            #pragma unroll
            for (int fj = 0; fj < 4; ++fj)
                acc[fi][fj] = __builtin_amdgcn_mfma_f32_16x16x32_bf16(
                    af[fi], bfr[fj], acc[fi][fj], 0, 0, 0);
        __builtin_amdgcn_s_setprio(0);
        asm volatile("s_barrier" ::: "memory");
        // ---- phase B: A frags fi 4-7; stage B halves of t+2 ----
        #pragma unroll
        for (int fi = 0; fi < 4; ++fi)
            af[fi] = *reinterpret_cast<const short8*>(
                &lds[cur + arow_s + (fi + 4) * 512]);
        if (t + 2 < NT) {
            const int nb = ((t + 2) & 3) * 16384 + 8192;
            stage_half(Bm, K, col0,       (t + 2) * BK, &lds[nb],        tid);
            stage_half(Bm, K, col0 + 128, (t + 2) * BK, &lds[nb + 4096], tid);
        }
        asm volatile("s_barrier" ::: "memory");
        __builtin_amdgcn_s_setprio(1);
        #pragma unroll
        for (int fi = 0; fi < 4; ++fi)
            #pragma unroll
            for (int fj = 0; fj < 4; ++fj)
                acc[fi + 4][fj] = __builtin_amdgcn_mfma_f32_16x16x32_bf16(
                    af[fi], bfr[fj], acc[fi + 4][fj], 0, 0, 0);
        __builtin_amdgcn_s_setprio(0);
        if (t + 1 < NT) {
            // gate tile t+1's data: only t+2's 4 stage-loads may stay in flight
            if (t + 2 < NT) asm volatile("s_waitcnt vmcnt(4)" ::: "memory");
            else            asm volatile("s_waitcnt vmcnt(0)" ::: "memory");
        }
        asm volatile("s_barrier" ::: "memory");
    }

    // epilogue
    #pragma unroll
    for (int fi = 0; fi < 8; ++fi) {
        #pragma unroll
        for (int fj = 0; fj < 4; ++fj) {
            #pragma unroll
            for (int q = 0; q < 4; ++q) {
                int m = row0 + wm * 128 + fi * 16 + kq * 4 + q;
                int n = col0 + wn * 64 + fj * 16 + l15;
                float v = acc[fi][fj][q];
                if (MODE == 0) {
                    C[(size_t)m * N + n] = v + bias0[n] + bias1[n];
                } else {
                    if (n < N) {
                        int t = m >> 7, b = m & 127;
                        C[(size_t)b * (Tt * Vv) + (size_t)t * Vv + n] = v + bias0[n];
                    }
                }
            }
        }
    }
}

// ---------------------------------------------------------------------------
// v13 gate MFMA (proven): W operands in REGISTERS (wreg[8][4] short8 =
// 128 VGPR), rotated h-gather. a0/a1 loads rotated per-WG; MFMA pairs
// a0[ks] with wreg[(ks+ROT)&7][nb] — all indices compile-time.
// ---------------------------------------------------------------------------
template<int ROT>
__device__ __forceinline__ void gate_mfma(
    const unsigned short* __restrict__ hprev,
    const short8 (&wreg)[8][4],
    int row0, int wave, int l15, int kq,
    floatx4 (&acc)[2][4])
{
    const short8* ar0 = reinterpret_cast<const short8*>(
        hprev + (size_t)(row0 + l15) * Hh) + wave * 32 + kq;
    const short8* ar1 = reinterpret_cast<const short8*>(
        hprev + (size_t)(row0 + 16 + l15) * Hh) + wave * 32 + kq;
    short8 a0[8], a1[8];
    #pragma unroll
    for (int ks = 0; ks < 8; ++ks) {
        const int j = (ks + ROT) & 7;
        a0[ks] = ar0[j * 4];
        a1[ks] = ar1[j * 4];
    }
    #pragma unroll
    for (int ks = 0; ks < 8; ++ks) {
        const int j = (ks + ROT) & 7;
        acc[0][0] = __builtin_amdgcn_mfma_f32_16x16x32_bf16(
            a0[ks], wreg[j][0], acc[0][0], 0, 0, 0);
        acc[0][1] = __builtin_amdgcn_mfma_f32_16x16x32_bf16(
            a0[ks], wreg[j][1], acc[0][1], 0, 0, 0);
        acc[0][2] = __builtin_amdgcn_mfma_f32_16x16x32_bf16(
            a0[ks], wreg[j][2], acc[0][2], 0, 0, 0);
        acc[0][3] = __builtin_amdgcn_mfma_f32_16x16x32_bf16(
            a0[ks], wreg[j][3], acc[0][3], 0, 0, 0);
    }
    #pragma unroll
    for (int ks = 0; ks < 8; ++ks) {
        const int j = (ks + ROT) & 7;
        acc[1][0] = __builtin_amdgcn_mfma_f32_16x16x32_bf16(
            a1[ks], wreg[j][0], acc[1][0], 0, 0, 0);
        acc[1][1] = __builtin_amdgcn_mfma_f32_16x16x32_bf16(
            a1[ks], wreg[j][1], acc[1][1], 0, 0, 0);
        acc[1][2] = __builtin_amdgcn_mfma_f32_16x16x32_bf16(
            a1[ks], wreg[j][2], acc[1][2], 0, 0, 0);
        acc[1][3] = __builtin_amdgcn_mfma_f32_16x16x32_bf16(
            a1[ks], wreg[j][3], acc[1][3], 0, 0, 0);
    }
}

// ---------------------------------------------------------------------------
// Persistent LSTM recurrence, v13 VERBATIM (proven: 338 us, passing).
// 256 WGs (all 256 CUs), 4 cohorts x 64 WGs, split-K waves, rotated gather,
// W-in-registers, counter-tree sync.
// (v14's XCD-local restructure failed correctness and is abandoned; its
// locality upside was small anyway — v13's cohort = w&3 already lands each
// cohort on only 2 XCDs under round-robin dispatch.)
// ---------------------------------------------------------------------------
__global__ __launch_bounds__(256, 1)
void lstm_persist(const unsigned short* __restrict__ whhb, // [4096][1024] bf16
                  const float* __restrict__ xg,            // [64*128][4096] f32
                  unsigned short* __restrict__ hsb,        // [64][128][1024] bf16
                  unsigned* __restrict__ flags) {          // 32 ctrs, 64B stride
    __shared__ float redsum[8 * 3 * 4 * 64];        // 24 KB  [c][slot][nb][lane]
    const int tid  = threadIdx.x;
    const int w    = blockIdx.x;
    const int wg_m = w & 3;        // row cohort: rows [wg_m*32, +32)
    const int wg_n = w >> 2;       // hcol slice (0..63)
    const int wave = tid >> 6;
    const int lane = tid & 63;
    const int l15  = lane & 15;
    const int kq   = lane >> 4;

    const int row0 = wg_m * 32;
    const int hcol = wg_n * 16 + l15;
    const int lrA = (wave >> 1) * 16 + kq * 4 + ((wave & 1) * 2);
    const int lrB = lrA + 1;
    const int rotsel = (wg_n >> 1) & 3;   // cycles 0..3 within an XCD
    unsigned* myctr = flags + (size_t)(wg_m * 8 + (wg_n >> 3)) * 16;
    float cell0 = 0.f, cell1 = 0.f;

    // W_hh fragments in registers, loaded once:
    // wreg[j][nb] = whhb[(nb*1024 + wg_n*16 + l15)*1024 + (wave*32+j*4+kq)*8]
    short8 wreg[8][4];
    {
        const unsigned short* wbase = whhb
            + (size_t)(wg_n * 16 + l15) * Hh + wave * 256 + kq * 8;
        #pragma unroll
        for (int nb = 0; nb < 4; ++nb)
            #pragma unroll
            for (int j = 0; j < 8; ++j)
                wreg[j][nb] = *reinterpret_cast<const short8*>(
                    wbase + (size_t)nb * Hh * Hh + j * 32);
    }

    float xa[2][4], xb[2][4];
    {
        const float* xrA = xg + (size_t)(row0 + lrA) * G + wg_n * 16 + l15;
        #pragma unroll
        for (int nb = 0; nb < 4; ++nb) {
            xa[0][nb] = xrA[nb * Hh];
            xa[1][nb] = xrA[G + nb * Hh];
        }
    }

#define WRC(W_, C_)                                                            \
    if (((C_) >> 1) != (W_)) {                                                 \
        _Pragma("unroll")                                                      \
        for (int nb = 0; nb < 4; ++nb)                                         \
            redsum[((C_) * 3 + (((W_) > ((C_) >> 1)) ? (W_)-1 : (W_))) * 256   \
                   + nb * 64 + lane] = acc[(C_) >> 2][nb][(C_) & 3];           \
    }

#define SPILL(W_)                                                              \
    do {                                                                       \
        _Pragma("unroll")                                                      \
        for (int nb = 0; nb < 4; ++nb) {                                       \
            own0[nb] = acc[(2 * (W_)) >> 2][nb][(2 * (W_)) & 3];               \
            own1[nb] = acc[(2 * (W_) + 1) >> 2][nb][(2 * (W_) + 1) & 3];       \
        }                                                                      \
        WRC(W_, 0); WRC(W_, 1); WRC(W_, 2); WRC(W_, 3);                        \
        WRC(W_, 4); WRC(W_, 5); WRC(W_, 6); WRC(W_, 7);                        \
    } while (0)

#define LSTM_STEP(T, XC, XN)                                                   \
    do {                                                                       \
        const int t_ = (T);                                                    \
        floatx4 acc[2][4];                                                     \
        _Pragma("unroll")                                                      \
        for (int i = 0; i < 2; ++i)                                            \
            _Pragma("unroll")                                                  \
            for (int j = 0; j < 4; ++j) acc[i][j] = (floatx4)0.f;              \
        if (t_ > 0) {                                                          \
            if (tid < 8) {                                                     \
                const unsigned* fl = flags + (size_t)(wg_m * 8 + tid) * 16;    \
                unsigned need = 8u * (unsigned)t_;                             \
                while (__hip_atomic_load(fl, __ATOMIC_RELAXED,                 \
                                         __HIP_MEMORY_SCOPE_AGENT) < need)     \
                    __builtin_amdgcn_s_sleep(1);                               \
            }                                                                  \
            __syncthreads();                                                   \
            asm volatile("" ::: "memory");                                     \
            const unsigned short* hprev = hsb + (size_t)(t_ - 1) * (Bb * Hh);  \
            if (rotsel == 0)                                                   \
                gate_mfma<0>(hprev, wreg, row0, wave, l15, kq, acc);           \
            else if (rotsel == 1)                                              \
                gate_mfma<2>(hprev, wreg, row0, wave, l15, kq, acc);           \
            else if (rotsel == 2)                                              \
                gate_mfma<4>(hprev, wreg, row0, wave, l15, kq, acc);           \
            else                                                               \
                gate_mfma<6>(hprev, wreg, row0, wave, l15, kq, acc);           \
        }                                                                      \
        float own0[4], own1[4];                                                \
        if (wave == 0)      SPILL(0);                                          \
        else if (wave == 1) SPILL(1);                                          \
        else if (wave == 2) SPILL(2);                                          \
        else                SPILL(3);                                          \
        __syncthreads();                                                       \
        float gA[4], gB[4];                                                    \
        {                                                                      \
            const int cA = wave * 2;                                           \
            _Pragma("unroll")                                                  \
            for (int nb = 0; nb < 4; ++nb) {                                   \
                int bA = (cA * 3) * 256 + nb * 64 + lane;                      \
                gA[nb] = own0[nb] + redsum[bA] + redsum[bA + 256]              \
                       + redsum[bA + 512] + XC[0][nb];                         \
                int bB = ((cA + 1) * 3) * 256 + nb * 64 + lane;                \
                gB[nb] = own1[nb] + redsum[bB] + redsum[bB + 256]              \
                       + redsum[bB + 512] + XC[1][nb];                         \
            }                                                                  \
        }                                                                      \
        unsigned short* ht = hsb + (size_t)t_ * (Bb * Hh);                     \
        {                                                                      \
            float si = sigmoid_fast(gA[0]);                                    \
            float sf = sigmoid_fast(gA[1]);                                    \
            float tg = tanh_fast(gA[2]);                                       \
            float so = sigmoid_fast(gA[3]);                                    \
            float cn = sf * cell0 + si * tg;                                   \
            cell0 = cn;                                                        \
            float h = so * tanh_fast(cn);                                      \
            __hip_atomic_store(&ht[(size_t)(row0 + lrA) * Hh + hcol], f2bf(h), \
                               __ATOMIC_RELAXED, __HIP_MEMORY_SCOPE_AGENT);    \
        }                                                                      \
        {                                                                      \
            float si = sigmoid_fast(gB[0]);                                    \
            float sf = sigmoid_fast(gB[1]);                                    \
            float tg = tanh_fast(gB[2]);                                       \
            float so = sigmoid_fast(gB[3]);                                    \
            float cn = sf * cell1 + si * tg;                                   \
            cell1 = cn;                                                        \
            float h = so * tanh_fast(cn);                                      \
            __hip_atomic_store(&ht[(size_t)(row0 + lrB) * Hh + hcol], f2bf(h), \
                               __ATOMIC_RELAXED, __HIP_MEMORY_SCOPE_AGENT);    \
        }                                                                      \
        __builtin_amdgcn_sched_barrier(0);                                     \
        if (t_ + 1 < Tt) {   /* xg prefetch: YOUNGEST VMEM (after stores) */   \
            const float* xrA = xg + (size_t)(t_ + 1) * (Bb * G)                \
                + (size_t)(row0 + lrA) * G + wg_n * 16 + l15;                  \
            _Pragma("unroll")                                                  \
            for (int nb = 0; nb < 4; ++nb) {                                   \
                XN[0][nb] = xrA[nb * Hh];                                      \
                XN[1][nb] = xrA[G + nb * Hh];                                  \
            }                                                                  \
        }                                                                      \
        __builtin_amdgcn_sched_barrier(0);                                     \
        if (t_ < Tt - 1) {                                                     \
            /* 2 h stores (oldest) + 8 xg loads outstanding: wait stores */    \
            asm volatile("s_waitcnt vmcnt(8)" ::: "memory");                   \
            __builtin_amdgcn_sched_barrier(0);                                 \
            __builtin_amdgcn_s_barrier();                                      \
            __builtin_amdgcn_sched_barrier(0);                                 \
            if (tid == 0)                                                      \
                __hip_atomic_fetch_add(myctr, 1u, __ATOMIC_RELAXED,            \
                                       __HIP_MEMORY_SCOPE_AGENT);              \
        }                                                                      \
    } while (0)

    for (int tt = 0; tt < Tt; tt += 2) {
        LSTM_STEP(tt,     xa, xb);
        LSTM_STEP(tt + 1, xb, xa);
    }
#undef LSTM_STEP
#undef SPILL
#undef WRC
}

// ---------------------------------------------------------------------------
extern "C" void kernel_launch(void* const* d_in, const int* in_sizes, int n_in,
                              void* d_out, int out_size, void* d_ws, size_t ws_size,
                              hipStream_t stream) {
    const float* features = (const float*)d_in[0];
    const int*   captions = (const int*)d_in[1];
    const float* embed_W  = (const float*)d_in[2];
    const float* W_ih     = (const float*)d_in[3];
    const float* W_hh     = (const float*)d_in[4];
    const float* b_ih     = (const float*)d_in[5];
    const float* b_hh     = (const float*)d_in[6];
    const float* fc_W     = (const float*)d_in[7];
    const float* fc_b     = (const float*)d_in[8];
    float* out = (float*)d_out;

    unsigned short* xsb  = (unsigned short*)d_ws;          // [8192][512]
    unsigned short* wihb = xsb  + (size_t)Tt * Bb * Ee;    // [4096][512]
    unsigned short* whhb = wihb + (size_t)G * Ee;          // [4096][1024]
    unsigned short* fcwb = whhb + (size_t)G * Hh;          // [10240][1024]
    unsigned short* hsb  = fcwb + (size_t)Vpad * Hh;       // [64][128][1024]
    float* xg = (float*)(hsb + (size_t)Tt * Bb * Hh);      // [8192][4096]
    unsigned* flags = (unsigned*)(xg + (size_t)Tt * Bb * G); // 32 ctrs, 64B stride

    (void)hipMemsetAsync(flags, 0, 128 * 32 * sizeof(unsigned), stream);

    // 1) fused weight conversions + input gather (one dispatch)
    prep<<<10240, 256, 0, stream>>>(W_ih, W_hh, fc_W, features, captions,
                                    embed_W, wihb, whhb, fcwb, xsb);

    // 2) x_gates = xs @ W_ih^T + b_ih + b_hh   (M=8192, N=4096, K=512)
    {
        dim3 grid(8192 / 256, G / 256);   // 32 x 16 = 512 wgs (%8 == 0)
        gemm256<0><<<grid, 512, 0, stream>>>(
            xsb, wihb, 8192, G, Ee, b_ih, b_hh, xg);
    }

    // 3) persistent LSTM recurrence (one launch, 64 steps, all 256 CUs)
    lstm_persist<<<256, 256, 0, stream>>>(whhb, xg, hsb, flags);

    // 4) out[b,t,v] = hs @ fc_W^T + fc_b   (M=8192, N=10000(pad 10240), K=1024)
    {
        dim3 grid(8192 / 256, Vpad / 256);  // 32 x 40 = 1280 wgs (%8 == 0)
        gemm256<2><<<grid, 512, 0, stream>>>(
            hsb, fcwb, 8192, Vv, Hh, fc_b, nullptr, out);
    }
}

// Round 12
// 641.243 us; speedup vs baseline: 1.3089x; 1.0215x over previous
//
#include <hip/hip_runtime.h>
#include <math.h>

// Problem constants
static constexpr int Bb = 128;    // batch
static constexpr int Tt = 64;     // seq len
static constexpr int Ee = 512;    // embed dim
static constexpr int Hh = 1024;   // hidden
static constexpr int Vv = 10000;  // vocab
static constexpr int G  = 4 * Hh; // 4096 gates
static constexpr int Vpad = 10240; // 40*256, zero-padded vocab rows (256-tiles)

typedef __attribute__((ext_vector_type(8))) short short8;
typedef __attribute__((ext_vector_type(4))) float floatx4;

__device__ __forceinline__ unsigned short f2bf(float f) {
    unsigned u = __float_as_uint(f);
    return (unsigned short)((u + 0x7fffu + ((u >> 16) & 1u)) >> 16);  // RNE
}

__device__ __forceinline__ void gload16(const void* g, void* l) {
    __builtin_amdgcn_global_load_lds(
        (const __attribute__((address_space(1))) void*)g,
        (__attribute__((address_space(3))) void*)l, 16, 0, 0);
}

// fast transcendentals (v_exp_f32 + v_rcp_f32; ~1e-6 rel err, far below bf16)
__device__ __forceinline__ float sigmoid_fast(float x) {
    return __builtin_amdgcn_rcpf(1.f + __expf(-x));
}
__device__ __forceinline__ float tanh_fast(float x) {
    float e = __expf(-2.f * fabsf(x));
    float t = (1.f - e) * __builtin_amdgcn_rcpf(1.f + e);
    return copysignf(t, x);
}

// ---------------------------------------------------------------------------
// Fused prep: 3x f32->bf16 weight converts + caption/feature gather in ONE
// dispatch. Block ranges: [0,1024) W_ih | [1024,3072) W_hh |
// [3072,8192) fc_W (pad to Vpad) | [8192,10240) gather xs.
// ---------------------------------------------------------------------------
__device__ __forceinline__ void cvt8_body(const float* __restrict__ s,
                                          unsigned short* __restrict__ d,
                                          int n, int i8) {
    short8 v;
    #pragma unroll
    for (int j = 0; j < 8; ++j) {
        int e = i8 + j;
        float f = (e < n) ? s[e] : 0.f;
        v[j] = (short)f2bf(f);
    }
    *reinterpret_cast<short8*>(d + i8) = v;
}

__global__ __launch_bounds__(256)
void prep(const float* __restrict__ W_ih, const float* __restrict__ W_hh,
          const float* __restrict__ fc_W, const float* __restrict__ features,
          const int* __restrict__ captions, const float* __restrict__ embed_W,
          unsigned short* __restrict__ wihb, unsigned short* __restrict__ whhb,
          unsigned short* __restrict__ fcwb, unsigned short* __restrict__ xsb) {
    const int blk = blockIdx.x;
    const int tid = threadIdx.x;
    if (blk < 1024) {
        cvt8_body(W_ih, wihb, G * Ee, (blk * 256 + tid) * 8);
    } else if (blk < 3072) {
        cvt8_body(W_hh, whhb, G * Hh, ((blk - 1024) * 256 + tid) * 8);
    } else if (blk < 8192) {
        cvt8_body(fc_W, fcwb, Vv * Hh, ((blk - 3072) * 256 + tid) * 8);
    } else {
        int idx = (blk - 8192) * 256 + tid;     // T*B*(E/8)
        int m  = idx >> 6;                      // row, 64 chunks per row
        int c8 = (idx & 63) * 8;
        int t = m >> 7;                         // m / B
        int b = m & 127;                        // m % B
        const float* src;
        if (t == 0) {
            src = features + (size_t)b * Ee + c8;
        } else {
            int tok = captions[(size_t)b * Tt + t];
            src = embed_W + (size_t)tok * Ee + c8;
        }
        short8 v;
        #pragma unroll
        for (int j = 0; j < 8; ++j) v[j] = (short)f2bf(src[j]);
        *reinterpret_cast<short8*>(xsb + (size_t)m * Ee + c8) = v;
    }
}

// ---------------------------------------------------------------------------
// 256x256-tile bf16 MFMA GEMM, BK=32, 4-deep circular LDS pipeline.
// v12-gemm changes (mechanism-backed, data-flow identical):
//  - MERGED single phase per K-tile: {12 ds_read | 4 stage(t+2) | setprio
//    32-MFMA cluster | vmcnt(4) | ONE s_barrier}. The previous 4 barriers/
//    tile were the m233 lockstep anti-pattern; with the 4-deep buffer one
//    barrier per tile is provably sufficient:
//      * writes in iter t target buf[(t+2)&3]; its last readers (iter t-2)
//        are fenced by >=2 intervening end-of-tile barriers;
//      * cross-wave staging visibility: each wave drains to vmcnt(4)
//        (leaving only t+2's own 4 loads) BEFORE the barrier, so after the
//        barrier every wave's reads of tile t+1 see landed data;
//      * max wave skew is 1 barrier: a wave in iter t coexists only with
//        waves >= iter t-1, and buf[(t+2)&3] differs from buf[(t-1..t+1)&3].
//  - IMPROVED SWIZZLE: slot = kq ^ ((l15>>1)&3) (was kq ^ (l15&3)), source
//    pre-swizzle c ^ (((r>>1)&3)<<4). Even-l15 lanes now hit 4 distinct
//    16B slots (was 2) -> ds_read_b128 conflict 4-way -> 2-way (free).
//    Involution: f(row) == (l15>>1)&3 on both A and B fragment rows (all
//    other row terms == 0 mod 4 after >>1); read phys chunk kq^f contains
//    logical chunk (kq^f)^f = kq.
// ---------------------------------------------------------------------------
__device__ __forceinline__ void stage_half(
    const unsigned short* __restrict__ Gsrc, int Kdim, int rowbase, int k0,
    unsigned short* ldsbase, int tid) {
    // one 16B load per thread covers the 8 KB half-tile (128 rows x 32 k)
    int e = tid * 16;                     // byte offset in half-tile
    int r = e >> 6;                       // row 0..127
    int c = e & 63;                       // byte in row (0/16/32/48)
    int c_log = c ^ (((r >> 1) & 3) << 4); // inverse-swizzled source column
    gload16(Gsrc + (size_t)(rowbase + r) * Kdim + k0 + (c_log >> 1),
            ldsbase + tid * 8);
}

template<int MODE>
__global__ __launch_bounds__(512, 2)
void gemm256(const unsigned short* __restrict__ A,
             const unsigned short* __restrict__ Bm,
             int M, int N, int K,
             const float* __restrict__ bias0, const float* __restrict__ bias1,
             float* __restrict__ C) {
    constexpr int BK = 32;
    __shared__ unsigned short lds[4 * 2 * 256 * BK];   // 128 KB

    const int nwg = gridDim.x * gridDim.y;
    const int flat = blockIdx.y * gridDim.x + blockIdx.x;
    const int tix = (flat & 7) * (nwg >> 3) + (flat >> 3);
    const int bx = tix % gridDim.x;
    const int by = tix / gridDim.x;

    const int tid  = threadIdx.x;
    const int wid  = tid >> 6;      // 0..7
    const int lane = tid & 63;
    const int wm = wid >> 2;        // 0..1  (M half)
    const int wn = wid & 3;         // 0..3  (N quarter)
    const int row0 = bx * 256;
    const int col0 = by * 256;
    const int l15 = lane & 15;
    const int kq  = lane >> 4;

    const int NT = K / BK;

    // per-thread ds_read bases (shorts); swizzled slot kq ^ ((l15>>1)&3)
    const int swz = (kq ^ ((l15 >> 1) & 3)) * 8;
    const int arow_s = wm * 4096 + l15 * 32 + swz;
    const int brow_s = 8192 + (wn >> 1) * 4096 + ((wn & 1) * 64 + l15) * 32 + swz;

    floatx4 acc[8][4];
    #pragma unroll
    for (int i = 0; i < 8; ++i)
        #pragma unroll
        for (int j = 0; j < 4; ++j) acc[i][j] = (floatx4)0.f;

    // prologue: stage tiles 0 and 1 (4 half-tiles each)
    stage_half(A,  K, row0,       0,  &lds[0],     tid);
    stage_half(A,  K, row0 + 128, 0,  &lds[4096],  tid);
    stage_half(Bm, K, col0,       0,  &lds[8192],  tid);
    stage_half(Bm, K, col0 + 128, 0,  &lds[12288], tid);
    stage_half(A,  K, row0,       BK, &lds[16384 + 0],     tid);
    stage_half(A,  K, row0 + 128, BK, &lds[16384 + 4096],  tid);
    stage_half(Bm, K, col0,       BK, &lds[16384 + 8192],  tid);
    stage_half(Bm, K, col0 + 128, BK, &lds[16384 + 12288], tid);
    asm volatile("s_waitcnt vmcnt(4)" ::: "memory");   // tile 0 landed
    asm volatile("s_barrier" ::: "memory");

    for (int t = 0; t < NT; ++t) {
        const int cur = (t & 3) * 16384;
        short8 af[8], bfr[4];
        #pragma unroll
        for (int fi = 0; fi < 8; ++fi)
            af[fi] = *reinterpret_cast<const short8*>(&lds[cur + arow_s + fi * 512]);
        #pragma unroll
        for (int fj = 0; fj < 4; ++fj)
            bfr[fj] = *reinterpret_cast<const short8*>(&lds[cur + brow_s + fj * 512]);
        if (t + 2 < NT) {   // stage tile t+2 into buf[(t+2)&3]
            const int nb = ((t + 2) & 3) * 16384;
            stage_half(A,  K, row0,       (t + 2) * BK, &lds[nb],         tid);
            stage_half(A,  K, row0 + 128, (t + 2) * BK, &lds[nb + 4096],  tid);
            stage_half(Bm, K, col0,       (t + 2) * BK, &lds[nb + 8192],  tid);
            stage_half(Bm, K, col0 + 128, (t + 2) * BK, &lds[nb + 12288], tid);
        }
        __builtin_amdgcn_s_setprio(1);
        #pragma unroll
        for (int fi = 0; fi < 8; ++fi)
            #pragma unroll
            for (int fj = 0; fj < 4; ++fj)
                acc[fi][fj] = __builtin_amdgcn_mfma_f32_16x16x32_bf16(
                    af[fi], bfr[fj], acc[fi][fj], 0, 0, 0);
        __builtin_amdgcn_s_setprio(0);
        if (t + 1 < NT) {
            // drain so tile t+1's loads are landed; only t+2's 4 stay in flight
            if (t + 2 < NT) asm volatile("s_waitcnt vmcnt(4)" ::: "memory");
            else            asm volatile("s_waitcnt vmcnt(0)" ::: "memory");
            asm volatile("s_barrier" ::: "memory");
        }
    }

    // epilogue
    #pragma unroll
    for (int fi = 0; fi < 8; ++fi) {
        #pragma unroll
        for (int fj = 0; fj < 4; ++fj) {
            #pragma unroll
            for (int q = 0; q < 4; ++q) {
                int m = row0 + wm * 128 + fi * 16 + kq * 4 + q;
                int n = col0 + wn * 64 + fj * 16 + l15;
                float v = acc[fi][fj][q];
                if (MODE == 0) {
                    C[(size_t)m * N + n] = v + bias0[n] + bias1[n];
                } else {
                    if (n < N) {
                        int t = m >> 7, b = m & 127;
                        C[(size_t)b * (Tt * Vv) + (size_t)t * Vv + n] = v + bias0[n];
                    }
                }
            }
        }
    }
}

// ---------------------------------------------------------------------------
// v13 gate MFMA (proven): W operands in REGISTERS (wreg[8][4] short8 =
// 128 VGPR), rotated h-gather. All indices compile-time.
// ---------------------------------------------------------------------------
template<int ROT>
__device__ __forceinline__ void gate_mfma(
    const unsigned short* __restrict__ hprev,
    const short8 (&wreg)[8][4],
    int row0, int wave, int l15, int kq,
    floatx4 (&acc)[2][4])
{
    const short8* ar0 = reinterpret_cast<const short8*>(
        hprev + (size_t)(row0 + l15) * Hh) + wave * 32 + kq;
    const short8* ar1 = reinterpret_cast<const short8*>(
        hprev + (size_t)(row0 + 16 + l15) * Hh) + wave * 32 + kq;
    short8 a0[8], a1[8];
    #pragma unroll
    for (int ks = 0; ks < 8; ++ks) {
        const int j = (ks + ROT) & 7;
        a0[ks] = ar0[j * 4];
        a1[ks] = ar1[j * 4];
    }
    #pragma unroll
    for (int ks = 0; ks < 8; ++ks) {
        const int j = (ks + ROT) & 7;
        acc[0][0] = __builtin_amdgcn_mfma_f32_16x16x32_bf16(
            a0[ks], wreg[j][0], acc[0][0], 0, 0, 0);
        acc[0][1] = __builtin_amdgcn_mfma_f32_16x16x32_bf16(
            a0[ks], wreg[j][1], acc[0][1], 0, 0, 0);
        acc[0][2] = __builtin_amdgcn_mfma_f32_16x16x32_bf16(
            a0[ks], wreg[j][2], acc[0][2], 0, 0, 0);
        acc[0][3] = __builtin_amdgcn_mfma_f32_16x16x32_bf16(
            a0[ks], wreg[j][3], acc[0][3], 0, 0, 0);
    }
    #pragma unroll
    for (int ks = 0; ks < 8; ++ks) {
        const int j = (ks + ROT) & 7;
        acc[1][0] = __builtin_amdgcn_mfma_f32_16x16x32_bf16(
            a1[ks], wreg[j][0], acc[1][0], 0, 0, 0);
        acc[1][1] = __builtin_amdgcn_mfma_f32_16x16x32_bf16(
            a1[ks], wreg[j][1], acc[1][1], 0, 0, 0);
        acc[1][2] = __builtin_amdgcn_mfma_f32_16x16x32_bf16(
            a1[ks], wreg[j][2], acc[1][2], 0, 0, 0);
        acc[1][3] = __builtin_amdgcn_mfma_f32_16x16x32_bf16(
            a1[ks], wreg[j][3], acc[1][3], 0, 0, 0);
    }
}

// ---------------------------------------------------------------------------
// Persistent LSTM recurrence, v13 VERBATIM (proven: 338-340 us, passing).
// 256 WGs (all 256 CUs), 4 cohorts x 64 WGs, split-K waves, rotated gather,
// W-in-registers, counter-tree sync.
// ---------------------------------------------------------------------------
__global__ __launch_bounds__(256, 1)
void lstm_persist(const unsigned short* __restrict__ whhb, // [4096][1024] bf16
                  const float* __restrict__ xg,            // [64*128][4096] f32
                  unsigned short* __restrict__ hsb,        // [64][128][1024] bf16
                  unsigned* __restrict__ flags) {          // 32 ctrs, 64B stride
    __shared__ float redsum[8 * 3 * 4 * 64];        // 24 KB  [c][slot][nb][lane]
    const int tid  = threadIdx.x;
    const int w    = blockIdx.x;
    const int wg_m = w & 3;        // row cohort: rows [wg_m*32, +32)
    const int wg_n = w >> 2;       // hcol slice (0..63)
    const int wave = tid >> 6;
    const int lane = tid & 63;
    const int l15  = lane & 15;
    const int kq   = lane >> 4;

    const int row0 = wg_m * 32;
    const int hcol = wg_n * 16 + l15;
    const int lrA = (wave >> 1) * 16 + kq * 4 + ((wave & 1) * 2);
    const int lrB = lrA + 1;
    const int rotsel = (wg_n >> 1) & 3;   // cycles 0..3 within an XCD
    unsigned* myctr = flags + (size_t)(wg_m * 8 + (wg_n >> 3)) * 16;
    float cell0 = 0.f, cell1 = 0.f;

    // W_hh fragments in registers, loaded once:
    // wreg[j][nb] = whhb[(nb*1024 + wg_n*16 + l15)*1024 + (wave*32+j*4+kq)*8]
    short8 wreg[8][4];
    {
        const unsigned short* wbase = whhb
            + (size_t)(wg_n * 16 + l15) * Hh + wave * 256 + kq * 8;
        #pragma unroll
        for (int nb = 0; nb < 4; ++nb)
            #pragma unroll
            for (int j = 0; j < 8; ++j)
                wreg[j][nb] = *reinterpret_cast<const short8*>(
                    wbase + (size_t)nb * Hh * Hh + j * 32);
    }

    float xa[2][4], xb[2][4];
    {
        const float* xrA = xg + (size_t)(row0 + lrA) * G + wg_n * 16 + l15;
        #pragma unroll
        for (int nb = 0; nb < 4; ++nb) {
            xa[0][nb] = xrA[nb * Hh];
            xa[1][nb] = xrA[G + nb * Hh];
        }
    }

#define WRC(W_, C_)                                                            \
    if (((C_) >> 1) != (W_)) {                                                 \
        _Pragma("unroll")                                                      \
        for (int nb = 0; nb < 4; ++nb)                                         \
            redsum[((C_) * 3 + (((W_) > ((C_) >> 1)) ? (W_)-1 : (W_))) * 256   \
                   + nb * 64 + lane] = acc[(C_) >> 2][nb][(C_) & 3];           \
    }

#define SPILL(W_)                                                              \
    do {                                                                       \
        _Pragma("unroll")                                                      \
        for (int nb = 0; nb < 4; ++nb) {                                       \
            own0[nb] = acc[(2 * (W_)) >> 2][nb][(2 * (W_)) & 3];               \
            own1[nb] = acc[(2 * (W_) + 1) >> 2][nb][(2 * (W_) + 1) & 3];       \
        }                                                                      \
        WRC(W_, 0); WRC(W_, 1); WRC(W_, 2); WRC(W_, 3);                        \
        WRC(W_, 4); WRC(W_, 5); WRC(W_, 6); WRC(W_, 7);                        \
    } while (0)

#define LSTM_STEP(T, XC, XN)                                                   \
    do {                                                                       \
        const int t_ = (T);                                                    \
        floatx4 acc[2][4];                                                     \
        _Pragma("unroll")                                                      \
        for (int i = 0; i < 2; ++i)                                            \
            _Pragma("unroll")                                                  \
            for (int j = 0; j < 4; ++j) acc[i][j] = (floatx4)0.f;              \
        if (t_ > 0) {                                                          \
            if (tid < 8) {                                                     \
                const unsigned* fl = flags + (size_t)(wg_m * 8 + tid) * 16;    \
                unsigned need = 8u * (unsigned)t_;                             \
                while (__hip_atomic_load(fl, __ATOMIC_RELAXED,                 \
                                         __HIP_MEMORY_SCOPE_AGENT) < need)     \
                    __builtin_amdgcn_s_sleep(1);                               \
            }                                                                  \
            __syncthreads();                                                   \
            asm volatile("" ::: "memory");                                     \
            const unsigned short* hprev = hsb + (size_t)(t_ - 1) * (Bb * Hh);  \
            if (rotsel == 0)                                                   \
                gate_mfma<0>(hprev, wreg, row0, wave, l15, kq, acc);           \
            else if (rotsel == 1)                                              \
                gate_mfma<2>(hprev, wreg, row0, wave, l15, kq, acc);           \
            else if (rotsel == 2)                                              \
                gate_mfma<4>(hprev, wreg, row0, wave, l15, kq, acc);           \
            else                                                               \
                gate_mfma<6>(hprev, wreg, row0, wave, l15, kq, acc);           \
        }                                                                      \
        float own0[4], own1[4];                                                \
        if (wave == 0)      SPILL(0);                                          \
        else if (wave == 1) SPILL(1);                                          \
        else if (wave == 2) SPILL(2);                                          \
        else                SPILL(3);                                          \
        __syncthreads();                                                       \
        float gA[4], gB[4];                                                    \
        {                                                                      \
            const int cA = wave * 2;                                           \
            _Pragma("unroll")                                                  \
            for (int nb = 0; nb < 4; ++nb) {                                   \
                int bA = (cA * 3) * 256 + nb * 64 + lane;                      \
                gA[nb] = own0[nb] + redsum[bA] + redsum[bA + 256]              \
                       + redsum[bA + 512] + XC[0][nb];                         \
                int bB = ((cA + 1) * 3) * 256 + nb * 64 + lane;                \
                gB[nb] = own1[nb] + redsum[bB] + redsum[bB + 256]              \
                       + redsum[bB + 512] + XC[1][nb];                         \
            }                                                                  \
        }                                                                      \
        unsigned short* ht = hsb + (size_t)t_ * (Bb * Hh);                     \
        {                                                                      \
            float si = sigmoid_fast(gA[0]);                                    \
            float sf = sigmoid_fast(gA[1]);                                    \
            float tg = tanh_fast(gA[2]);                                       \
            float so = sigmoid_fast(gA[3]);                                    \
            float cn = sf * cell0 + si * tg;                                   \
            cell0 = cn;                                                        \
            float h = so * tanh_fast(cn);                                      \
            __hip_atomic_store(&ht[(size_t)(row0 + lrA) * Hh + hcol], f2bf(h), \
                               __ATOMIC_RELAXED, __HIP_MEMORY_SCOPE_AGENT);    \
        }                                                                      \
        {                                                                      \
            float si = sigmoid_fast(gB[0]);                                    \
            float sf = sigmoid_fast(gB[1]);                                    \
            float tg = tanh_fast(gB[2]);                                       \
            float so = sigmoid_fast(gB[3]);                                    \
            float cn = sf * cell1 + si * tg;                                   \
            cell1 = cn;                                                        \
            float h = so * tanh_fast(cn);                                      \
            __hip_atomic_store(&ht[(size_t)(row0 + lrB) * Hh + hcol], f2bf(h), \
                               __ATOMIC_RELAXED, __HIP_MEMORY_SCOPE_AGENT);    \
        }                                                                      \
        __builtin_amdgcn_sched_barrier(0);                                     \
        if (t_ + 1 < Tt) {   /* xg prefetch: YOUNGEST VMEM (after stores) */   \
            const float* xrA = xg + (size_t)(t_ + 1) * (Bb * G)                \
                + (size_t)(row0 + lrA) * G + wg_n * 16 + l15;                  \
            _Pragma("unroll")                                                  \
            for (int nb = 0; nb < 4; ++nb) {                                   \
                XN[0][nb] = xrA[nb * Hh];                                      \
                XN[1][nb] = xrA[G + nb * Hh];                                  \
            }                                                                  \
        }                                                                      \
        __builtin_amdgcn_sched_barrier(0);                                     \
        if (t_ < Tt - 1) {                                                     \
            /* 2 h stores (oldest) + 8 xg loads outstanding: wait stores */    \
            asm volatile("s_waitcnt vmcnt(8)" ::: "memory");                   \
            __builtin_amdgcn_sched_barrier(0);                                 \
            __builtin_amdgcn_s_barrier();                                      \
            __builtin_amdgcn_sched_barrier(0);                                 \
            if (tid == 0)                                                      \
                __hip_atomic_fetch_add(myctr, 1u, __ATOMIC_RELAXED,            \
                                       __HIP_MEMORY_SCOPE_AGENT);              \
        }                                                                      \
    } while (0)

    for (int tt = 0; tt < Tt; tt += 2) {
        LSTM_STEP(tt,     xa, xb);
        LSTM_STEP(tt + 1, xb, xa);
    }
#undef LSTM_STEP
#undef SPILL
#undef WRC
}

// ---------------------------------------------------------------------------
extern "C" void kernel_launch(void* const* d_in, const int* in_sizes, int n_in,
                              void* d_out, int out_size, void* d_ws, size_t ws_size,
                              hipStream_t stream) {
    const float* features = (const float*)d_in[0];
    const int*   captions = (const int*)d_in[1];
    const float* embed_W  = (const float*)d_in[2];
    const float* W_ih     = (const float*)d_in[3];
    const float* W_hh     = (const float*)d_in[4];
    const float* b_ih     = (const float*)d_in[5];
    const float* b_hh     = (const float*)d_in[6];
    const float* fc_W     = (const float*)d_in[7];
    const float* fc_b     = (const float*)d_in[8];
    float* out = (float*)d_out;

    unsigned short* xsb  = (unsigned short*)d_ws;          // [8192][512]
    unsigned short* wihb = xsb  + (size_t)Tt * Bb * Ee;    // [4096][512]
    unsigned short* whhb = wihb + (size_t)G * Ee;          // [4096][1024]
    unsigned short* fcwb = whhb + (size_t)G * Hh;          // [10240][1024]
    unsigned short* hsb  = fcwb + (size_t)Vpad * Hh;       // [64][128][1024]
    float* xg = (float*)(hsb + (size_t)Tt * Bb * Hh);      // [8192][4096]
    unsigned* flags = (unsigned*)(xg + (size_t)Tt * Bb * G); // 32 ctrs, 64B stride

    (void)hipMemsetAsync(flags, 0, 128 * 32 * sizeof(unsigned), stream);

    // 1) fused weight conversions + input gather (one dispatch)
    prep<<<10240, 256, 0, stream>>>(W_ih, W_hh, fc_W, features, captions,
                                    embed_W, wihb, whhb, fcwb, xsb);

    // 2) x_gates = xs @ W_ih^T + b_ih + b_hh   (M=8192, N=4096, K=512)
    {
        dim3 grid(8192 / 256, G / 256);   // 32 x 16 = 512 wgs (%8 == 0)
        gemm256<0><<<grid, 512, 0, stream>>>(
            xsb, wihb, 8192, G, Ee, b_ih, b_hh, xg);
    }

    // 3) persistent LSTM recurrence (one launch, 64 steps, all 256 CUs)
    lstm_persist<<<256, 256, 0, stream>>>(whhb, xg, hsb, flags);

    // 4) out[b,t,v] = hs @ fc_W^T + fc_b   (M=8192, N=10000(pad 10240), K=1024)
    {
        dim3 grid(8192 / 256, Vpad / 256);  // 32 x 40 = 1280 wgs (%8 == 0)
        gemm256<2><<<grid, 512, 0, stream>>>(
            hsb, fcwb, 8192, Vv, Hh, fc_b, nullptr, out);
    }
}

// Round 14
// 637.595 us; speedup vs baseline: 1.3164x; 1.0057x over previous
//
#include <hip/hip_runtime.h>
#include <math.h>

// Problem constants
static constexpr int Bb = 128;    // batch
static constexpr int Tt = 64;     // seq len
static constexpr int Ee = 512;    // embed dim
static constexpr int Hh = 1024;   // hidden
static constexpr int Vv = 10000;  // vocab
static constexpr int G  = 4 * Hh; // 4096 gates
static constexpr int Vpad = 10240; // 40*256, zero-padded vocab rows (256-tiles)

typedef __attribute__((ext_vector_type(8))) short short8;
typedef __attribute__((ext_vector_type(4))) float floatx4;

__device__ __forceinline__ unsigned short f2bf(float f) {
    unsigned u = __float_as_uint(f);
    return (unsigned short)((u + 0x7fffu + ((u >> 16) & 1u)) >> 16);  // RNE
}

__device__ __forceinline__ void gload16(const void* g, void* l) {
    __builtin_amdgcn_global_load_lds(
        (const __attribute__((address_space(1))) void*)g,
        (__attribute__((address_space(3))) void*)l, 16, 0, 0);
}

// fast transcendentals (v_exp_f32 + v_rcp_f32; ~1e-6 rel err, far below bf16)
__device__ __forceinline__ float sigmoid_fast(float x) {
    return __builtin_amdgcn_rcpf(1.f + __expf(-x));
}
__device__ __forceinline__ float tanh_fast(float x) {
    float e = __expf(-2.f * fabsf(x));
    float t = (1.f - e) * __builtin_amdgcn_rcpf(1.f + e);
    return copysignf(t, x);
}

// ---------------------------------------------------------------------------
// Fused prep: 3x f32->bf16 weight converts + caption/feature gather in ONE
// dispatch. Block ranges: [0,1024) W_ih | [1024,3072) W_hh |
// [3072,8192) fc_W (pad to Vpad) | [8192,10240) gather xs.
// ---------------------------------------------------------------------------
__device__ __forceinline__ void cvt8_body(const float* __restrict__ s,
                                          unsigned short* __restrict__ d,
                                          int n, int i8) {
    short8 v;
    #pragma unroll
    for (int j = 0; j < 8; ++j) {
        int e = i8 + j;
        float f = (e < n) ? s[e] : 0.f;
        v[j] = (short)f2bf(f);
    }
    *reinterpret_cast<short8*>(d + i8) = v;
}

__global__ __launch_bounds__(256)
void prep(const float* __restrict__ W_ih, const float* __restrict__ W_hh,
          const float* __restrict__ fc_W, const float* __restrict__ features,
          const int* __restrict__ captions, const float* __restrict__ embed_W,
          unsigned short* __restrict__ wihb, unsigned short* __restrict__ whhb,
          unsigned short* __restrict__ fcwb, unsigned short* __restrict__ xsb) {
    const int blk = blockIdx.x;
    const int tid = threadIdx.x;
    if (blk < 1024) {
        cvt8_body(W_ih, wihb, G * Ee, (blk * 256 + tid) * 8);
    } else if (blk < 3072) {
        cvt8_body(W_hh, whhb, G * Hh, ((blk - 1024) * 256 + tid) * 8);
    } else if (blk < 8192) {
        cvt8_body(fc_W, fcwb, Vv * Hh, ((blk - 3072) * 256 + tid) * 8);
    } else {
        int idx = (blk - 8192) * 256 + tid;     // T*B*(E/8)
        int m  = idx >> 6;                      // row, 64 chunks per row
        int c8 = (idx & 63) * 8;
        int t = m >> 7;                         // m / B
        int b = m & 127;                        // m % B
        const float* src;
        if (t == 0) {
            src = features + (size_t)b * Ee + c8;
        } else {
            int tok = captions[(size_t)b * Tt + t];
            src = embed_W + (size_t)tok * Ee + c8;
        }
        short8 v;
        #pragma unroll
        for (int j = 0; j < 8; ++j) v[j] = (short)f2bf(src[j]);
        *reinterpret_cast<short8*>(xsb + (size_t)m * Ee + c8) = v;
    }
}

// ---------------------------------------------------------------------------
// 256x256-tile bf16 MFMA GEMM, BK=32, 4-deep circular LDS pipeline,
// merged single-phase per K-tile + improved swizzle (R12, proven 641us).
// R13 addition: MODE-2 epilogue guard hoisted to a wave-uniform branch
// (39/40 col tiles take the unguarded path); edge tile keeps the original
// guarded loop verbatim. No address algebra changed.
// ---------------------------------------------------------------------------
__device__ __forceinline__ void stage_half(
    const unsigned short* __restrict__ Gsrc, int Kdim, int rowbase, int k0,
    unsigned short* ldsbase, int tid) {
    // one 16B load per thread covers the 8 KB half-tile (128 rows x 32 k)
    int e = tid * 16;                     // byte offset in half-tile
    int r = e >> 6;                       // row 0..127
    int c = e & 63;                       // byte in row (0/16/32/48)
    int c_log = c ^ (((r >> 1) & 3) << 4); // inverse-swizzled source column
    gload16(Gsrc + (size_t)(rowbase + r) * Kdim + k0 + (c_log >> 1),
            ldsbase + tid * 8);
}

template<int MODE>
__global__ __launch_bounds__(512, 2)
void gemm256(const unsigned short* __restrict__ A,
             const unsigned short* __restrict__ Bm,
             int M, int N, int K,
             const float* __restrict__ bias0, const float* __restrict__ bias1,
             float* __restrict__ C) {
    constexpr int BK = 32;
    __shared__ unsigned short lds[4 * 2 * 256 * BK];   // 128 KB

    const int nwg = gridDim.x * gridDim.y;
    const int flat = blockIdx.y * gridDim.x + blockIdx.x;
    const int tix = (flat & 7) * (nwg >> 3) + (flat >> 3);
    const int bx = tix % gridDim.x;
    const int by = tix / gridDim.x;

    const int tid  = threadIdx.x;
    const int wid  = tid >> 6;      // 0..7
    const int lane = tid & 63;
    const int wm = wid >> 2;        // 0..1  (M half)
    const int wn = wid & 3;         // 0..3  (N quarter)
    const int row0 = bx * 256;
    const int col0 = by * 256;
    const int l15 = lane & 15;
    const int kq  = lane >> 4;

    const int NT = K / BK;

    // per-thread ds_read bases (shorts); swizzled slot kq ^ ((l15>>1)&3)
    const int swz = (kq ^ ((l15 >> 1) & 3)) * 8;
    const int arow_s = wm * 4096 + l15 * 32 + swz;
    const int brow_s = 8192 + (wn >> 1) * 4096 + ((wn & 1) * 64 + l15) * 32 + swz;

    floatx4 acc[8][4];
    #pragma unroll
    for (int i = 0; i < 8; ++i)
        #pragma unroll
        for (int j = 0; j < 4; ++j) acc[i][j] = (floatx4)0.f;

    // prologue: stage tiles 0 and 1 (4 half-tiles each)
    stage_half(A,  K, row0,       0,  &lds[0],     tid);
    stage_half(A,  K, row0 + 128, 0,  &lds[4096],  tid);
    stage_half(Bm, K, col0,       0,  &lds[8192],  tid);
    stage_half(Bm, K, col0 + 128, 0,  &lds[12288], tid);
    stage_half(A,  K, row0,       BK, &lds[16384 + 0],     tid);
    stage_half(A,  K, row0 + 128, BK, &lds[16384 + 4096],  tid);
    stage_half(Bm, K, col0,       BK, &lds[16384 + 8192],  tid);
    stage_half(Bm, K, col0 + 128, BK, &lds[16384 + 12288], tid);
    asm volatile("s_waitcnt vmcnt(4)" ::: "memory");   // tile 0 landed
    asm volatile("s_barrier" ::: "memory");

    for (int t = 0; t < NT; ++t) {
        const int cur = (t & 3) * 16384;
        short8 af[8], bfr[4];
        #pragma unroll
        for (int fi = 0; fi < 8; ++fi)
            af[fi] = *reinterpret_cast<const short8*>(&lds[cur + arow_s + fi * 512]);
        #pragma unroll
        for (int fj = 0; fj < 4; ++fj)
            bfr[fj] = *reinterpret_cast<const short8*>(&lds[cur + brow_s + fj * 512]);
        if (t + 2 < NT) {   // stage tile t+2 into buf[(t+2)&3]
            const int nb = ((t + 2) & 3) * 16384;
            stage_half(A,  K, row0,       (t + 2) * BK, &lds[nb],         tid);
            stage_half(A,  K, row0 + 128, (t + 2) * BK, &lds[nb + 4096],  tid);
            stage_half(Bm, K, col0,       (t + 2) * BK, &lds[nb + 8192],  tid);
            stage_half(Bm, K, col0 + 128, (t + 2) * BK, &lds[nb + 12288], tid);
        }
        __builtin_amdgcn_s_setprio(1);
        #pragma unroll
        for (int fi = 0; fi < 8; ++fi)
            #pragma unroll
            for (int fj = 0; fj < 4; ++fj)
                acc[fi][fj] = __builtin_amdgcn_mfma_f32_16x16x32_bf16(
                    af[fi], bfr[fj], acc[fi][fj], 0, 0, 0);
        __builtin_amdgcn_s_setprio(0);
        if (t + 1 < NT) {
            if (t + 2 < NT) asm volatile("s_waitcnt vmcnt(4)" ::: "memory");
            else            asm volatile("s_waitcnt vmcnt(0)" ::: "memory");
            asm volatile("s_barrier" ::: "memory");
        }
    }

    // epilogue
    if (MODE == 0) {
        #pragma unroll
        for (int fi = 0; fi < 8; ++fi)
            #pragma unroll
            for (int fj = 0; fj < 4; ++fj)
                #pragma unroll
                for (int q = 0; q < 4; ++q) {
                    int m = row0 + wm * 128 + fi * 16 + kq * 4 + q;
                    int n = col0 + wn * 64 + fj * 16 + l15;
                    C[(size_t)m * N + n] = acc[fi][fj][q] + bias0[n] + bias1[n];
                }
    } else if (col0 + 256 <= N) {
        // fast path: whole tile in-bounds (wave-uniform), no per-elem guard
        #pragma unroll
        for (int fi = 0; fi < 8; ++fi)
            #pragma unroll
            for (int fj = 0; fj < 4; ++fj)
                #pragma unroll
                for (int q = 0; q < 4; ++q) {
                    int m = row0 + wm * 128 + fi * 16 + kq * 4 + q;
                    int n = col0 + wn * 64 + fj * 16 + l15;
                    int t = m >> 7, b = m & 127;
                    C[(size_t)b * (Tt * Vv) + (size_t)t * Vv + n] =
                        acc[fi][fj][q] + bias0[n];
                }
    } else {
        #pragma unroll
        for (int fi = 0; fi < 8; ++fi)
            #pragma unroll
            for (int fj = 0; fj < 4; ++fj)
                #pragma unroll
                for (int q = 0; q < 4; ++q) {
                    int m = row0 + wm * 128 + fi * 16 + kq * 4 + q;
                    int n = col0 + wn * 64 + fj * 16 + l15;
                    if (n < N) {
                        int t = m >> 7, b = m & 127;
                        C[(size_t)b * (Tt * Vv) + (size_t)t * Vv + n] =
                            acc[fi][fj][q] + bias0[n];
                    }
                }
    }
}

// ---------------------------------------------------------------------------
// v13 gate MFMA (proven): W operands in REGISTERS (wreg[8][4] short8 =
// 128 VGPR), rotated h-gather. All indices compile-time.
// ---------------------------------------------------------------------------
template<int ROT>
__device__ __forceinline__ void gate_mfma(
    const unsigned short* __restrict__ hprev,
    const short8 (&wreg)[8][4],
    int row0, int wave, int l15, int kq,
    floatx4 (&acc)[2][4])
{
    const short8* ar0 = reinterpret_cast<const short8*>(
        hprev + (size_t)(row0 + l15) * Hh) + wave * 32 + kq;
    const short8* ar1 = reinterpret_cast<const short8*>(
        hprev + (size_t)(row0 + 16 + l15) * Hh) + wave * 32 + kq;
    short8 a0[8], a1[8];
    #pragma unroll
    for (int ks = 0; ks < 8; ++ks) {
        const int j = (ks + ROT) & 7;
        a0[ks] = ar0[j * 4];
        a1[ks] = ar1[j * 4];
    }
    #pragma unroll
    for (int ks = 0; ks < 8; ++ks) {
        const int j = (ks + ROT) & 7;
        acc[0][0] = __builtin_amdgcn_mfma_f32_16x16x32_bf16(
            a0[ks], wreg[j][0], acc[0][0], 0, 0, 0);
        acc[0][1] = __builtin_amdgcn_mfma_f32_16x16x32_bf16(
            a0[ks], wreg[j][1], acc[0][1], 0, 0, 0);
        acc[0][2] = __builtin_amdgcn_mfma_f32_16x16x32_bf16(
            a0[ks], wreg[j][2], acc[0][2], 0, 0, 0);
        acc[0][3] = __builtin_amdgcn_mfma_f32_16x16x32_bf16(
            a0[ks], wreg[j][3], acc[0][3], 0, 0, 0);
    }
    #pragma unroll
    for (int ks = 0; ks < 8; ++ks) {
        const int j = (ks + ROT) & 7;
        acc[1][0] = __builtin_amdgcn_mfma_f32_16x16x32_bf16(
            a1[ks], wreg[j][0], acc[1][0], 0, 0, 0);
        acc[1][1] = __builtin_amdgcn_mfma_f32_16x16x32_bf16(
            a1[ks], wreg[j][1], acc[1][1], 0, 0, 0);
        acc[1][2] = __builtin_amdgcn_mfma_f32_16x16x32_bf16(
            a1[ks], wreg[j][2], acc[1][2], 0, 0, 0);
        acc[1][3] = __builtin_amdgcn_mfma_f32_16x16x32_bf16(
            a1[ks], wreg[j][3], acc[1][3], 0, 0, 0);
    }
}

// ---------------------------------------------------------------------------
// Persistent LSTM recurrence, v13 VERBATIM — FROZEN.
// 256 WGs (all 256 CUs), 4 cohorts x 64 WGs, split-K waves, rotated gather,
// W-in-registers, counter-tree sync. Proven 338-341 us, passing.
// DO NOT restructure ownership/reduction: v9, v14, v15 all failed
// correctness (absmax 0.12-0.38) on rewrites of this logic; v12's sync
// change regressed 50%. Wins came only from traffic changes (v8 WG-count,
// v11 rotation, v13 W-in-regs) that kept the v8 ownership algebra intact.
// ---------------------------------------------------------------------------
__global__ __launch_bounds__(256, 1)
void lstm_persist(const unsigned short* __restrict__ whhb, // [4096][1024] bf16
                  const float* __restrict__ xg,            // [64*128][4096] f32
                  unsigned short* __restrict__ hsb,        // [64][128][1024] bf16
                  unsigned* __restrict__ flags) {          // 32 ctrs, 64B stride
    __shared__ float redsum[8 * 3 * 4 * 64];        // 24 KB  [c][slot][nb][lane]
    const int tid  = threadIdx.x;
    const int w    = blockIdx.x;
    const int wg_m = w & 3;        // row cohort: rows [wg_m*32, +32)
    const int wg_n = w >> 2;       // hcol slice (0..63)
    const int wave = tid >> 6;
    const int lane = tid & 63;
    const int l15  = lane & 15;
    const int kq   = lane >> 4;

    const int row0 = wg_m * 32;
    const int hcol = wg_n * 16 + l15;
    const int lrA = (wave >> 1) * 16 + kq * 4 + ((wave & 1) * 2);
    const int lrB = lrA + 1;
    const int rotsel = (wg_n >> 1) & 3;   // cycles 0..3 within an XCD
    unsigned* myctr = flags + (size_t)(wg_m * 8 + (wg_n >> 3)) * 16;
    float cell0 = 0.f, cell1 = 0.f;

    // W_hh fragments in registers, loaded once:
    // wreg[j][nb] = whhb[(nb*1024 + wg_n*16 + l15)*1024 + (wave*32+j*4+kq)*8]
    short8 wreg[8][4];
    {
        const unsigned short* wbase = whhb
            + (size_t)(wg_n * 16 + l15) * Hh + wave * 256 + kq * 8;
        #pragma unroll
        for (int nb = 0; nb < 4; ++nb)
            #pragma unroll
            for (int j = 0; j < 8; ++j)
                wreg[j][nb] = *reinterpret_cast<const short8*>(
                    wbase + (size_t)nb * Hh * Hh + j * 32);
    }

    float xa[2][4], xb[2][4];
    {
        const float* xrA = xg + (size_t)(row0 + lrA) * G + wg_n * 16 + l15;
        #pragma unroll
        for (int nb = 0; nb < 4; ++nb) {
            xa[0][nb] = xrA[nb * Hh];
            xa[1][nb] = xrA[G + nb * Hh];
        }
    }

#define WRC(W_, C_)                                                            \
    if (((C_) >> 1) != (W_)) {                                                 \
        _Pragma("unroll")                                                      \
        for (int nb = 0; nb < 4; ++nb)                                         \
            redsum[((C_) * 3 + (((W_) > ((C_) >> 1)) ? (W_)-1 : (W_))) * 256   \
                   + nb * 64 + lane] = acc[(C_) >> 2][nb][(C_) & 3];           \
    }

#define SPILL(W_)                                                              \
    do {                                                                       \
        _Pragma("unroll")                                                      \
        for (int nb = 0; nb < 4; ++nb) {                                       \
            own0[nb] = acc[(2 * (W_)) >> 2][nb][(2 * (W_)) & 3];               \
            own1[nb] = acc[(2 * (W_) + 1) >> 2][nb][(2 * (W_) + 1) & 3];       \
        }                                                                      \
        WRC(W_, 0); WRC(W_, 1); WRC(W_, 2); WRC(W_, 3);                        \
        WRC(W_, 4); WRC(W_, 5); WRC(W_, 6); WRC(W_, 7);                        \
    } while (0)

#define LSTM_STEP(T, XC, XN)                                                   \
    do {                                                                       \
        const int t_ = (T);                                                    \
        floatx4 acc[2][4];                                                     \
        _Pragma("unroll")                                                      \
        for (int i = 0; i < 2; ++i)                                            \
            _Pragma("unroll")                                                  \
            for (int j = 0; j < 4; ++j) acc[i][j] = (floatx4)0.f;              \
        if (t_ > 0) {                                                          \
            if (tid < 8) {                                                     \
                const unsigned* fl = flags + (size_t)(wg_m * 8 + tid) * 16;    \
                unsigned need = 8u * (unsigned)t_;                             \
                while (__hip_atomic_load(fl, __ATOMIC_RELAXED,                 \
                                         __HIP_MEMORY_SCOPE_AGENT) < need)     \
                    __builtin_amdgcn_s_sleep(1);                               \
            }                                                                  \
            __syncthreads();                                                   \
            asm volatile("" ::: "memory");                                     \
            const unsigned short* hprev = hsb + (size_t)(t_ - 1) * (Bb * Hh);  \
            if (rotsel == 0)                                                   \
                gate_mfma<0>(hprev, wreg, row0, wave, l15, kq, acc);           \
            else if (rotsel == 1)                                              \
                gate_mfma<2>(hprev, wreg, row0, wave, l15, kq, acc);           \
            else if (rotsel == 2)                                              \
                gate_mfma<4>(hprev, wreg, row0, wave, l15, kq, acc);           \
            else                                                               \
                gate_mfma<6>(hprev, wreg, row0, wave, l15, kq, acc);           \
        }                                                                      \
        float own0[4], own1[4];                                                \
        if (wave == 0)      SPILL(0);                                          \
        else if (wave == 1) SPILL(1);                                          \
        else if (wave == 2) SPILL(2);                                          \
        else                SPILL(3);                                          \
        __syncthreads();                                                       \
        float gA[4], gB[4];                                                    \
        {                                                                      \
            const int cA = wave * 2;                                           \
            _Pragma("unroll")                                                  \
            for (int nb = 0; nb < 4; ++nb) {                                   \
                int bA = (cA * 3) * 256 + nb * 64 + lane;                      \
                gA[nb] = own0[nb] + redsum[bA] + redsum[bA + 256]              \
                       + redsum[bA + 512] + XC[0][nb];                         \
                int bB = ((cA + 1) * 3) * 256 + nb * 64 + lane;                \
                gB[nb] = own1[nb] + redsum[bB] + redsum[bB + 256]              \
                       + redsum[bB + 512] + XC[1][nb];                         \
            }                                                                  \
        }                                                                      \
        unsigned short* ht = hsb + (size_t)t_ * (Bb * Hh);                     \
        {                                                                      \
            float si = sigmoid_fast(gA[0]);                                    \
            float sf = sigmoid_fast(gA[1]);                                    \
            float tg = tanh_fast(gA[2]);                                       \
            float so = sigmoid_fast(gA[3]);                                    \
            float cn = sf * cell0 + si * tg;                                   \
            cell0 = cn;                                                        \
            float h = so * tanh_fast(cn);                                      \
            __hip_atomic_store(&ht[(size_t)(row0 + lrA) * Hh + hcol], f2bf(h), \
                               __ATOMIC_RELAXED, __HIP_MEMORY_SCOPE_AGENT);    \
        }                                                                      \
        {                                                                      \
            float si = sigmoid_fast(gB[0]);                                    \
            float sf = sigmoid_fast(gB[1]);                                    \
            float tg = tanh_fast(gB[2]);                                       \
            float so = sigmoid_fast(gB[3]);                                    \
            float cn = sf * cell1 + si * tg;                                   \
            cell1 = cn;                                                        \
            float h = so * tanh_fast(cn);                                      \
            __hip_atomic_store(&ht[(size_t)(row0 + lrB) * Hh + hcol], f2bf(h), \
                               __ATOMIC_RELAXED, __HIP_MEMORY_SCOPE_AGENT);    \
        }                                                                      \
        __builtin_amdgcn_sched_barrier(0);                                     \
        if (t_ + 1 < Tt) {   /* xg prefetch: YOUNGEST VMEM (after stores) */   \
            const float* xrA = xg + (size_t)(t_ + 1) * (Bb * G)                \
                + (size_t)(row0 + lrA) * G + wg_n * 16 + l15;                  \
            _Pragma("unroll")                                                  \
            for (int nb = 0; nb < 4; ++nb) {                                   \
                XN[0][nb] = xrA[nb * Hh];                                      \
                XN[1][nb] = xrA[G + nb * Hh];                                  \
            }                                                                  \
        }                                                                      \
        __builtin_amdgcn_sched_barrier(0);                                     \
        if (t_ < Tt - 1) {                                                     \
            /* 2 h stores (oldest) + 8 xg loads outstanding: wait stores */    \
            asm volatile("s_waitcnt vmcnt(8)" ::: "memory");                   \
            __builtin_amdgcn_sched_barrier(0);                                 \
            __builtin_amdgcn_s_barrier();                                      \
            __builtin_amdgcn_sched_barrier(0);                                 \
            if (tid == 0)                                                      \
                __hip_atomic_fetch_add(myctr, 1u, __ATOMIC_RELAXED,            \
                                       __HIP_MEMORY_SCOPE_AGENT);              \
        }                                                                      \
    } while (0)

    for (int tt = 0; tt < Tt; tt += 2) {
        LSTM_STEP(tt,     xa, xb);
        LSTM_STEP(tt + 1, xb, xa);
    }
#undef LSTM_STEP
#undef SPILL
#undef WRC
}

// ---------------------------------------------------------------------------
extern "C" void kernel_launch(void* const* d_in, const int* in_sizes, int n_in,
                              void* d_out, int out_size, void* d_ws, size_t ws_size,
                              hipStream_t stream) {
    const float* features = (const float*)d_in[0];
    const int*   captions = (const int*)d_in[1];
    const float* embed_W  = (const float*)d_in[2];
    const float* W_ih     = (const float*)d_in[3];
    const float* W_hh     = (const float*)d_in[4];
    const float* b_ih     = (const float*)d_in[5];
    const float* b_hh     = (const float*)d_in[6];
    const float* fc_W     = (const float*)d_in[7];
    const float* fc_b     = (const float*)d_in[8];
    float* out = (float*)d_out;

    unsigned short* xsb  = (unsigned short*)d_ws;          // [8192][512]
    unsigned short* wihb = xsb  + (size_t)Tt * Bb * Ee;    // [4096][512]
    unsigned short* whhb = wihb + (size_t)G * Ee;          // [4096][1024]
    unsigned short* fcwb = whhb + (size_t)G * Hh;          // [10240][1024]
    unsigned short* hsb  = fcwb + (size_t)Vpad * Hh;       // [64][128][1024]
    float* xg = (float*)(hsb + (size_t)Tt * Bb * Hh);      // [8192][4096]
    unsigned* flags = (unsigned*)(xg + (size_t)Tt * Bb * G); // 32 ctrs, 64B stride

    (void)hipMemsetAsync(flags, 0, 128 * 32 * sizeof(unsigned), stream);

    // 1) fused weight conversions + input gather (one dispatch)
    prep<<<10240, 256, 0, stream>>>(W_ih, W_hh, fc_W, features, captions,
                                    embed_W, wihb, whhb, fcwb, xsb);

    // 2) x_gates = xs @ W_ih^T + b_ih + b_hh   (M=8192, N=4096, K=512)
    {
        dim3 grid(8192 / 256, G / 256);   // 32 x 16 = 512 wgs (%8 == 0)
        gemm256<0><<<grid, 512, 0, stream>>>(
            xsb, wihb, 8192, G, Ee, b_ih, b_hh, xg);
    }

    // 3) persistent LSTM recurrence (one launch, 64 steps, all 256 CUs)
    lstm_persist<<<256, 256, 0, stream>>>(whhb, xg, hsb, flags);

    // 4) out[b,t,v] = hs @ fc_W^T + fc_b   (M=8192, N=10000(pad 10240), K=1024)
    {
        dim3 grid(8192 / 256, Vpad / 256);  // 32 x 40 = 1280 wgs (%8 == 0)
        gemm256<2><<<grid, 512, 0, stream>>>(
            hsb, fcwb, 8192, Vv, Hh, fc_b, nullptr, out);
    }
}